// Round 1
// baseline (853.582 us; speedup 1.0000x reference)
//
#include <hip/hip_runtime.h>
#include <hip/hip_bf16.h>
#include <math.h>

typedef __bf16 bf16;
typedef __bf16 bf16x8 __attribute__((ext_vector_type(8)));
typedef __bf16 bf16x4 __attribute__((ext_vector_type(4)));
typedef float f32x4 __attribute__((ext_vector_type(4)));

#define S_LEN 2048
#define NTOK 8192          // B*S
#define DIM 1024
#define NH 16
#define HEADD 64
#define DFF 4096
#define MODD 6144          // 6*D

// async global->LDS, 16B per lane; LDS side must be wave-uniform base + lane*16
__device__ __forceinline__ void gload_lds16(const bf16* g, bf16* l) {
  __builtin_amdgcn_global_load_lds(
      (const __attribute__((address_space(1))) void*)g,
      (__attribute__((address_space(3))) void*)l, 16, 0, 0);
}

__device__ __forceinline__ float gelu_tanh(float x) {
  float inner = 0.7978845608028654f * (x + 0.044715f * x * x * x);
  return 0.5f * x * (1.0f + tanhf(inner));
}

// ---------------- mod = c @ ada_W + ada_b ----------------
__global__ __launch_bounds__(256) void init_mod_kernel(
    const float* __restrict__ ada_b, float* __restrict__ mod) {
  int i = blockIdx.x * 256 + threadIdx.x;   // 0..24575
  mod[i] = ada_b[i % MODD];
}

__global__ __launch_bounds__(256) void ada_gemm_kernel(
    const float* __restrict__ cnd, const float* __restrict__ W,
    float* __restrict__ mod) {
  int n = blockIdx.x * 256 + threadIdx.x;   // 0..6143
  int k0 = blockIdx.y * 128;
  float a0 = 0.f, a1 = 0.f, a2 = 0.f, a3 = 0.f;
  for (int k = k0; k < k0 + 128; ++k) {
    float w = W[(size_t)k * MODD + n];
    a0 = fmaf(cnd[k], w, a0);
    a1 = fmaf(cnd[1024 + k], w, a1);
    a2 = fmaf(cnd[2048 + k], w, a2);
    a3 = fmaf(cnd[3072 + k], w, a3);
  }
  atomicAdd(&mod[n], a0);
  atomicAdd(&mod[MODD + n], a1);
  atomicAdd(&mod[2 * MODD + n], a2);
  atomicAdd(&mod[3 * MODD + n], a3);
}

// ---------------- W (K,N) fp32 -> Wt (N,K) bf16 ----------------
__global__ __launch_bounds__(256) void transpose_cast_kernel(
    const float* __restrict__ W, bf16* __restrict__ Wt, int K, int N) {
  __shared__ float tile[32][33];
  int n0 = blockIdx.x * 32, k0 = blockIdx.y * 32;
  int r = threadIdx.x >> 3;
  int c4 = (threadIdx.x & 7) * 4;
  float4 v = *(const float4*)&W[(size_t)(k0 + r) * N + n0 + c4];
  tile[r][c4 + 0] = v.x; tile[r][c4 + 1] = v.y;
  tile[r][c4 + 2] = v.z; tile[r][c4 + 3] = v.w;
  __syncthreads();
  bf16x4 o;
  o[0] = (bf16)tile[c4 + 0][r];
  o[1] = (bf16)tile[c4 + 1][r];
  o[2] = (bf16)tile[c4 + 2][r];
  o[3] = (bf16)tile[c4 + 3][r];
  *(bf16x4*)&Wt[(size_t)(n0 + r) * K + k0 + c4] = o;
}

// ---------------- LayerNorm + adaLN modulate -> bf16 ----------------
__global__ __launch_bounds__(256) void ln_mod_kernel(
    const float* __restrict__ x, const float* __restrict__ w,
    const float* __restrict__ mod, int sh_off, int sc_off,
    bf16* __restrict__ out) {
  __shared__ float red[8];
  const int row = blockIdx.x;
  const int b = row >> 11;          // row / 2048
  const int tid = threadIdx.x;
  const float4 v = ((const float4*)(x + (size_t)row * DIM))[tid];
  float s1 = v.x + v.y + v.z + v.w;
  float s2 = v.x * v.x + v.y * v.y + v.z * v.z + v.w * v.w;
  for (int off = 32; off > 0; off >>= 1) {
    s1 += __shfl_down(s1, off, 64);
    s2 += __shfl_down(s2, off, 64);
  }
  const int wid = tid >> 6;
  if ((tid & 63) == 0) { red[wid] = s1; red[4 + wid] = s2; }
  __syncthreads();
  s1 = red[0] + red[1] + red[2] + red[3];
  s2 = red[4] + red[5] + red[6] + red[7];
  const float mu = s1 * (1.0f / DIM);
  const float inv = rsqrtf(s2 * (1.0f / DIM) - mu * mu + 1e-5f);
  const int c = tid * 4;
  const float* mb = mod + (size_t)b * MODD;
  float xs[4] = {v.x, v.y, v.z, v.w};
  bf16x4 o;
#pragma unroll
  for (int j = 0; j < 4; ++j)
    o[j] = (bf16)(((xs[j] - mu) * inv) * w[c + j] * (1.0f + mb[sc_off + c + j]) +
                  mb[sh_off + c + j]);
  *(bf16x4*)(out + (size_t)row * DIM + c) = o;
}

// ---------------- bf16 MFMA GEMM, C = A(M,K) @ Bt(N,K)^T, fused epilogues ----
// EPI 0: Cb = bf16(acc)                       (qkv)
// EPI 1: Cf = resid + g[b,n]*acc              (Wout proj -> d_out)
// EPI 2: Cb = bf16(gelu(acc + bias))          (W1)
// EPI 3: Cf = resid + g[b,n]*(acc + bias)     (W2 -> d_out, in place)
template <int EPI>
__global__ __launch_bounds__(256) void gemm_bt(
    const bf16* __restrict__ A, const bf16* __restrict__ Bt,
    bf16* __restrict__ Cb, float* __restrict__ Cf,
    const float* __restrict__ bias, const float* __restrict__ gmod,
    const float* __restrict__ resid, int M, int N, int K) {
  __shared__ __align__(16) bf16 As[128 * 32];
  __shared__ __align__(16) bf16 Bs[128 * 32];
  const int tid = threadIdx.x;
  const int wid = tid >> 6;
  const int lane = tid & 63;
  const int l15 = lane & 15;
  const int quad = lane >> 4;
  const int m0 = blockIdx.y * 128;
  const int n0 = blockIdx.x * 128;
  const int wm = (wid & 1) * 64;
  const int wn = (wid >> 1) * 64;

  const int r0 = tid >> 2;           // 0..63
  const int cc0 = (tid & 3) * 8;     // k-chunk offset in elements
  const size_t a_base = (size_t)(m0 + r0) * K + cc0;
  const size_t a_base2 = (size_t)(m0 + 64 + r0) * K + cc0;
  const size_t b_base = (size_t)(n0 + r0) * K + cc0;
  const size_t b_base2 = (size_t)(n0 + 64 + r0) * K + cc0;
  bf16* As_d = &As[tid * 8];
  bf16* As_d2 = &As[(256 + tid) * 8];
  bf16* Bs_d = &Bs[tid * 8];
  bf16* Bs_d2 = &Bs[(256 + tid) * 8];

  f32x4 acc[4][4] = {};

  for (int kt = 0; kt < K; kt += 32) {
    gload_lds16(A + a_base + kt, As_d);
    gload_lds16(A + a_base2 + kt, As_d2);
    gload_lds16(Bt + b_base + kt, Bs_d);
    gload_lds16(Bt + b_base2 + kt, Bs_d2);
    __syncthreads();
    bf16x8 af[4], bfr[4];
#pragma unroll
    for (int i = 0; i < 4; ++i) {
      af[i] = *(const bf16x8*)&As[(wm + i * 16 + l15) * 32 + quad * 8];
      bfr[i] = *(const bf16x8*)&Bs[(wn + i * 16 + l15) * 32 + quad * 8];
    }
#pragma unroll
    for (int i = 0; i < 4; ++i)
#pragma unroll
      for (int j = 0; j < 4; ++j)
        acc[i][j] = __builtin_amdgcn_mfma_f32_16x16x32_bf16(af[i], bfr[j],
                                                            acc[i][j], 0, 0, 0);
    __syncthreads();
  }

#pragma unroll
  for (int i = 0; i < 4; ++i) {
#pragma unroll
    for (int r = 0; r < 4; ++r) {
      const int m = m0 + wm + i * 16 + quad * 4 + r;   // C row = quad*4+reg
#pragma unroll
      for (int j = 0; j < 4; ++j) {
        const int n = n0 + wn + j * 16 + l15;          // C col = lane&15
        float v = acc[i][j][r];
        if (EPI == 0) {
          Cb[(size_t)m * N + n] = (bf16)v;
        } else if (EPI == 1) {
          const int b = m >> 11;
          Cf[(size_t)m * N + n] =
              resid[(size_t)m * N + n] + gmod[(size_t)b * MODD + n] * v;
        } else if (EPI == 2) {
          v += bias[n];
          Cb[(size_t)m * N + n] = (bf16)gelu_tanh(v);
        } else {
          v += bias[n];
          const int b = m >> 11;
          Cf[(size_t)m * N + n] =
              resid[(size_t)m * N + n] + gmod[(size_t)b * MODD + n] * v;
        }
      }
    }
  }
}

// ---------------- RMSNorm + RoPE on q,k (in place, one wave = one (token,h)) --
__global__ __launch_bounds__(256) void rope_kernel(
    bf16* __restrict__ qkv, const float* __restrict__ cosb,
    const float* __restrict__ sinb, const float* __restrict__ qw,
    const float* __restrict__ kw) {
  const int wid = threadIdx.x >> 6;
  const int lane = threadIdx.x & 63;
  const int inst = blockIdx.x * 4 + wid;   // 0..B*S*NH-1
  const int h = inst & (NH - 1);
  const int token = inst >> 4;
  const int s = token & (S_LEN - 1);
  const size_t base = (size_t)token * (3 * DIM) + h * HEADD + lane;
  const float cv = cosb[s * HEADD + lane];
  const float sv = sinb[s * HEADD + lane];
  const float sign = (lane < 32) ? -1.0f : 1.0f;
  {
    float xq = (float)qkv[base];
    float ss = xq * xq;
    for (int off = 1; off < 64; off <<= 1) ss += __shfl_xor(ss, off, 64);
    float rn = rsqrtf(ss * (1.0f / HEADD) + 1e-6f);
    float xn = xq * rn * qw[lane];
    float other = __shfl_xor(xn, 32, 64);
    qkv[base] = (bf16)(xn * cv + sign * other * sv);
  }
  {
    float xk = (float)qkv[base + DIM];
    float ss = xk * xk;
    for (int off = 1; off < 64; off <<= 1) ss += __shfl_xor(ss, off, 64);
    float rn = rsqrtf(ss * (1.0f / HEADD) + 1e-6f);
    float xn = xk * rn * kw[lane];
    float other = __shfl_xor(xn, 32, 64);
    qkv[base + DIM] = (bf16)(xn * cv + sign * other * sv);
  }
}

// ---------------- flash attention: 64 q-rows/block, 64-key tiles ----------
__global__ __launch_bounds__(256) void attn_kernel(
    const bf16* __restrict__ qkv, bf16* __restrict__ out) {
  __shared__ __align__(16) bf16 Ks[64][72];       // [key][feat], +8 pad
  __shared__ __align__(16) bf16 Vt[64][72];       // [feat][key], +8 pad
  __shared__ __align__(16) bf16 Ps[4][16][72];    // per-wave P round trip
  const int bh = blockIdx.y;
  const int b = bh >> 4;
  const int h = bh & 15;
  const int q0 = blockIdx.x * 64;
  const int tid = threadIdx.x;
  const int wid = tid >> 6;
  const int lane = tid & 63;
  const int l15 = lane & 15;
  const int quad = lane >> 4;

  const int qrow = q0 + wid * 16 + l15;
  const size_t qbase = (size_t)(b * S_LEN + qrow) * (3 * DIM) + h * HEADD;
  const bf16x8 aq0 = *(const bf16x8*)(qkv + qbase + quad * 8);
  const bf16x8 aq1 = *(const bf16x8*)(qkv + qbase + 32 + quad * 8);

  f32x4 oacc[4] = {};
  float mrow[4] = {-1e30f, -1e30f, -1e30f, -1e30f};
  float lrow[4] = {0.f, 0.f, 0.f, 0.f};

  for (int kt = 0; kt < S_LEN; kt += 64) {
    __syncthreads();   // previous iteration's reads done before restage
#pragma unroll
    for (int rep = 0; rep < 2; ++rep) {
      const int idx = rep * 256 + tid;          // 0..511
      const int r = idx >> 3;                   // key row 0..63
      const int c8 = (idx & 7) * 8;             // feature chunk
      const size_t kb =
          (size_t)(b * S_LEN + kt + r) * (3 * DIM) + DIM + h * HEADD + c8;
      *(bf16x8*)&Ks[r][c8] = *(const bf16x8*)(qkv + kb);
      const bf16x8 vv = *(const bf16x8*)(qkv + kb + DIM);
#pragma unroll
      for (int j = 0; j < 8; ++j) Vt[c8 + j][r] = vv[j];
    }
    __syncthreads();

    // S = Q K^T  (16 q-rows x 64 keys per wave)
    f32x4 sc[4] = {};
#pragma unroll
    for (int cc = 0; cc < 4; ++cc) {
      const bf16x8 b0 = *(const bf16x8*)&Ks[cc * 16 + l15][quad * 8];
      const bf16x8 b1 = *(const bf16x8*)&Ks[cc * 16 + l15][32 + quad * 8];
      sc[cc] = __builtin_amdgcn_mfma_f32_16x16x32_bf16(aq0, b0, sc[cc], 0, 0, 0);
      sc[cc] = __builtin_amdgcn_mfma_f32_16x16x32_bf16(aq1, b1, sc[cc], 0, 0, 0);
    }

    // online softmax (rows are quad*4+r; reduce across 16 lanes of quad group)
    float mnew[4], alpha[4];
#pragma unroll
    for (int r = 0; r < 4; ++r) {
      float tm = fmaxf(fmaxf(sc[0][r], sc[1][r]), fmaxf(sc[2][r], sc[3][r])) * 0.125f;
#pragma unroll
      for (int off = 1; off < 16; off <<= 1) tm = fmaxf(tm, __shfl_xor(tm, off, 64));
      const float mn = fmaxf(mrow[r], tm);
      mnew[r] = mn;
      alpha[r] = __expf(mrow[r] - mn);
      mrow[r] = mn;
    }
    float psum[4] = {0.f, 0.f, 0.f, 0.f};
#pragma unroll
    for (int cc = 0; cc < 4; ++cc) {
#pragma unroll
      for (int r = 0; r < 4; ++r) {
        const float p = __expf(sc[cc][r] * 0.125f - mnew[r]);
        psum[r] += p;
        Ps[wid][quad * 4 + r][cc * 16 + l15] = (bf16)p;   // C-layout -> LDS
      }
    }
#pragma unroll
    for (int r = 0; r < 4; ++r) {
      float ps = psum[r];
#pragma unroll
      for (int off = 1; off < 16; off <<= 1) ps += __shfl_xor(ps, off, 64);
      lrow[r] = lrow[r] * alpha[r] + ps;
#pragma unroll
      for (int j = 0; j < 4; ++j) oacc[j][r] *= alpha[r];
    }

    // P (A-layout from LDS) @ V
    const bf16x8 pa0 = *(const bf16x8*)&Ps[wid][l15][quad * 8];
    const bf16x8 pa1 = *(const bf16x8*)&Ps[wid][l15][32 + quad * 8];
#pragma unroll
    for (int j = 0; j < 4; ++j) {
      const bf16x8 v0 = *(const bf16x8*)&Vt[j * 16 + l15][quad * 8];
      const bf16x8 v1 = *(const bf16x8*)&Vt[j * 16 + l15][32 + quad * 8];
      oacc[j] = __builtin_amdgcn_mfma_f32_16x16x32_bf16(pa0, v0, oacc[j], 0, 0, 0);
      oacc[j] = __builtin_amdgcn_mfma_f32_16x16x32_bf16(pa1, v1, oacc[j], 0, 0, 0);
    }
  }

#pragma unroll
  for (int r = 0; r < 4; ++r) {
    const int m = q0 + wid * 16 + quad * 4 + r;
    const float invl = 1.0f / lrow[r];
#pragma unroll
    for (int j = 0; j < 4; ++j)
      out[((size_t)(b * S_LEN + m) * NH + h) * HEADD + j * 16 + l15] =
          (bf16)(oacc[j][r] * invl);
  }
}

// ---------------- launcher ----------------
extern "C" void kernel_launch(void* const* d_in, const int* in_sizes, int n_in,
                              void* d_out, int out_size, void* d_ws,
                              size_t ws_size, hipStream_t stream) {
  const float* x = (const float*)d_in[0];
  const float* cosb = (const float*)d_in[1];
  const float* sinb = (const float*)d_in[2];
  const float* cnd = (const float*)d_in[3];
  const float* norm1_w = (const float*)d_in[4];
  const float* Wqkv = (const float*)d_in[5];
  const float* Wout = (const float*)d_in[6];
  const float* q_norm_w = (const float*)d_in[7];
  const float* k_norm_w = (const float*)d_in[8];
  const float* norm2_w = (const float*)d_in[9];
  const float* W1 = (const float*)d_in[10];
  const float* b1 = (const float*)d_in[11];
  const float* W2 = (const float*)d_in[12];
  const float* b2 = (const float*)d_in[13];
  const float* ada_W = (const float*)d_in[14];
  const float* ada_b = (const float*)d_in[15];
  float* out = (float*)d_out;

  char* p = (char*)d_ws;
  float* mod = (float*)p;   p += (size_t)4 * MODD * 4;        // (4,6144) f32
  bf16* WqkvT = (bf16*)p;   p += (size_t)3072 * 1024 * 2;
  bf16* WoutT = (bf16*)p;   p += (size_t)1024 * 1024 * 2;
  bf16* W1T = (bf16*)p;     p += (size_t)4096 * 1024 * 2;
  bf16* W2T = (bf16*)p;     p += (size_t)1024 * 4096 * 2;
  bf16* XN = (bf16*)p;      p += (size_t)NTOK * DIM * 2;      // ln1 out, reused ln2
  bf16* QKV = (bf16*)p;     p += (size_t)NTOK * 3 * DIM * 2;  // qkv / q,k roped in place
  bf16* ATTN = (bf16*)p;    p += (size_t)NTOK * DIM * 2;
  bf16* Hbuf = (bf16*)p;    p += (size_t)NTOK * DFF * 2;

  init_mod_kernel<<<96, 256, 0, stream>>>(ada_b, mod);
  ada_gemm_kernel<<<dim3(24, 8), 256, 0, stream>>>(cnd, ada_W, mod);
  transpose_cast_kernel<<<dim3(96, 32), 256, 0, stream>>>(Wqkv, WqkvT, 1024, 3072);
  transpose_cast_kernel<<<dim3(32, 32), 256, 0, stream>>>(Wout, WoutT, 1024, 1024);
  transpose_cast_kernel<<<dim3(128, 32), 256, 0, stream>>>(W1, W1T, 1024, 4096);
  transpose_cast_kernel<<<dim3(32, 128), 256, 0, stream>>>(W2, W2T, 4096, 1024);
  ln_mod_kernel<<<NTOK, 256, 0, stream>>>(x, norm1_w, mod, 0, 1024, XN);
  gemm_bt<0><<<dim3(24, 64), 256, 0, stream>>>(XN, WqkvT, QKV, nullptr, nullptr,
                                               nullptr, nullptr, NTOK, 3072, 1024);
  rope_kernel<<<NTOK * NH / 4, 256, 0, stream>>>(QKV, cosb, sinb, q_norm_w, k_norm_w);
  attn_kernel<<<dim3(32, 64), 256, 0, stream>>>(QKV, ATTN);
  gemm_bt<1><<<dim3(8, 64), 256, 0, stream>>>(ATTN, WoutT, nullptr, out, nullptr,
                                              mod + 2 * 1024, x, NTOK, 1024, 1024);
  ln_mod_kernel<<<NTOK, 256, 0, stream>>>(out, norm2_w, mod, 3 * 1024, 4 * 1024, XN);
  gemm_bt<2><<<dim3(32, 64), 256, 0, stream>>>(XN, W1T, Hbuf, nullptr, b1, nullptr,
                                               nullptr, NTOK, DFF, 1024);
  gemm_bt<3><<<dim3(8, 64), 256, 0, stream>>>(Hbuf, W2T, nullptr, out, b2,
                                              mod + 5 * 1024, out, NTOK, 1024, DFF);
  (void)in_sizes; (void)n_in; (void)out_size; (void)ws_size;
}

// Round 2
// 723.029 us; speedup vs baseline: 1.1806x; 1.1806x over previous
//
#include <hip/hip_runtime.h>
#include <hip/hip_bf16.h>
#include <math.h>

typedef __bf16 bf16;
typedef __bf16 bf16x8 __attribute__((ext_vector_type(8)));
typedef __bf16 bf16x4 __attribute__((ext_vector_type(4)));
typedef float f32x4 __attribute__((ext_vector_type(4)));

#define S_LEN 2048
#define NTOK 8192          // B*S
#define DIM 1024
#define NH 16
#define HEADD 64
#define DFF 4096
#define MODD 6144          // 6*D

// async global->LDS, 16B per lane; LDS side must be wave-uniform base + lane*16
__device__ __forceinline__ void gload_lds16(const bf16* g, bf16* l) {
  __builtin_amdgcn_global_load_lds(
      (const __attribute__((address_space(1))) void*)g,
      (__attribute__((address_space(3))) void*)l, 16, 0, 0);
}

__device__ __forceinline__ float gelu_tanh(float x) {
  float inner = 0.7978845608028654f * (x + 0.044715f * x * x * x);
  return 0.5f * x * (1.0f + tanhf(inner));
}

// ---------------- mod = c @ ada_W + ada_b ----------------
__global__ __launch_bounds__(256) void init_mod_kernel(
    const float* __restrict__ ada_b, float* __restrict__ mod) {
  int i = blockIdx.x * 256 + threadIdx.x;   // 0..24575
  mod[i] = ada_b[i % MODD];
}

__global__ __launch_bounds__(256) void ada_gemm_kernel(
    const float* __restrict__ cnd, const float* __restrict__ W,
    float* __restrict__ mod) {
  int n = blockIdx.x * 256 + threadIdx.x;   // 0..6143
  int k0 = blockIdx.y * 128;
  float a0 = 0.f, a1 = 0.f, a2 = 0.f, a3 = 0.f;
  for (int k = k0; k < k0 + 128; ++k) {
    float w = W[(size_t)k * MODD + n];
    a0 = fmaf(cnd[k], w, a0);
    a1 = fmaf(cnd[1024 + k], w, a1);
    a2 = fmaf(cnd[2048 + k], w, a2);
    a3 = fmaf(cnd[3072 + k], w, a3);
  }
  atomicAdd(&mod[n], a0);
  atomicAdd(&mod[MODD + n], a1);
  atomicAdd(&mod[2 * MODD + n], a2);
  atomicAdd(&mod[3 * MODD + n], a3);
}

// ---------------- W (K,N) fp32 -> Wt (N,K) bf16 ----------------
__global__ __launch_bounds__(256) void transpose_cast_kernel(
    const float* __restrict__ W, bf16* __restrict__ Wt, int K, int N) {
  __shared__ float tile[32][33];
  int n0 = blockIdx.x * 32, k0 = blockIdx.y * 32;
  int r = threadIdx.x >> 3;
  int c4 = (threadIdx.x & 7) * 4;
  float4 v = *(const float4*)&W[(size_t)(k0 + r) * N + n0 + c4];
  tile[r][c4 + 0] = v.x; tile[r][c4 + 1] = v.y;
  tile[r][c4 + 2] = v.z; tile[r][c4 + 3] = v.w;
  __syncthreads();
  bf16x4 o;
  o[0] = (bf16)tile[c4 + 0][r];
  o[1] = (bf16)tile[c4 + 1][r];
  o[2] = (bf16)tile[c4 + 2][r];
  o[3] = (bf16)tile[c4 + 3][r];
  *(bf16x4*)&Wt[(size_t)(n0 + r) * K + k0 + c4] = o;
}

// ---------------- V part of qkv -> VT[b][h][d][s] ----------------
__global__ __launch_bounds__(256) void vtrans_kernel(
    const bf16* __restrict__ qkv, bf16* __restrict__ VT) {
  __shared__ __align__(16) bf16 t[64][72];
  const int bh = blockIdx.y;
  const int b = bh >> 4, h = bh & 15;
  const int s0 = blockIdx.x * 64;
  const int tid = threadIdx.x;
  // stage: row r = s-offset, 16 dims per thread
  {
    const int r = tid >> 2;
    const int c = (tid & 3) * 16;
    const bf16* src =
        qkv + (size_t)(b * S_LEN + s0 + r) * 3072 + 2048 + h * 64 + c;
    *(bf16x8*)&t[r][c] = *(const bf16x8*)src;
    *(bf16x8*)&t[r][c + 8] = *(const bf16x8*)(src + 8);
  }
  __syncthreads();
  // write: lane d = tid&63 (conflict-free LDS reads), s-chunk = (tid>>6)*16
  {
    const int d = tid & 63;
    const int sc = (tid >> 6) * 16;
    bf16x8 o0, o1;
#pragma unroll
    for (int j = 0; j < 8; ++j) o0[j] = t[sc + j][d];
#pragma unroll
    for (int j = 0; j < 8; ++j) o1[j] = t[sc + 8 + j][d];
    bf16* dst = VT + (size_t)(bh * 64 + d) * S_LEN + s0 + sc;
    *(bf16x8*)dst = o0;
    *(bf16x8*)(dst + 8) = o1;
  }
}

// ---------------- LayerNorm + adaLN modulate -> bf16 ----------------
__global__ __launch_bounds__(256) void ln_mod_kernel(
    const float* __restrict__ x, const float* __restrict__ w,
    const float* __restrict__ mod, int sh_off, int sc_off,
    bf16* __restrict__ out) {
  __shared__ float red[8];
  const int row = blockIdx.x;
  const int b = row >> 11;          // row / 2048
  const int tid = threadIdx.x;
  const float4 v = ((const float4*)(x + (size_t)row * DIM))[tid];
  float s1 = v.x + v.y + v.z + v.w;
  float s2 = v.x * v.x + v.y * v.y + v.z * v.z + v.w * v.w;
  for (int off = 32; off > 0; off >>= 1) {
    s1 += __shfl_down(s1, off, 64);
    s2 += __shfl_down(s2, off, 64);
  }
  const int wid = tid >> 6;
  if ((tid & 63) == 0) { red[wid] = s1; red[4 + wid] = s2; }
  __syncthreads();
  s1 = red[0] + red[1] + red[2] + red[3];
  s2 = red[4] + red[5] + red[6] + red[7];
  const float mu = s1 * (1.0f / DIM);
  const float inv = rsqrtf(s2 * (1.0f / DIM) - mu * mu + 1e-5f);
  const int c = tid * 4;
  const float* mb = mod + (size_t)b * MODD;
  float xs[4] = {v.x, v.y, v.z, v.w};
  bf16x4 o;
#pragma unroll
  for (int j = 0; j < 4; ++j)
    o[j] = (bf16)(((xs[j] - mu) * inv) * w[c + j] * (1.0f + mb[sc_off + c + j]) +
                  mb[sh_off + c + j]);
  *(bf16x4*)(out + (size_t)row * DIM + c) = o;
}

// ---------------- bf16 MFMA GEMM, C = A(M,K) @ Bt(N,K)^T, fused epilogues ----
template <int EPI>
__global__ __launch_bounds__(256) void gemm_bt(
    const bf16* __restrict__ A, const bf16* __restrict__ Bt,
    bf16* __restrict__ Cb, float* __restrict__ Cf,
    const float* __restrict__ bias, const float* __restrict__ gmod,
    const float* __restrict__ resid, int M, int N, int K) {
  __shared__ __align__(16) bf16 As[128 * 32];
  __shared__ __align__(16) bf16 Bs[128 * 32];
  const int tid = threadIdx.x;
  const int wid = tid >> 6;
  const int lane = tid & 63;
  const int l15 = lane & 15;
  const int quad = lane >> 4;
  const int m0 = blockIdx.y * 128;
  const int n0 = blockIdx.x * 128;
  const int wm = (wid & 1) * 64;
  const int wn = (wid >> 1) * 64;

  const int r0 = tid >> 2;           // 0..63
  const int cc0 = (tid & 3) * 8;     // k-chunk offset in elements
  const size_t a_base = (size_t)(m0 + r0) * K + cc0;
  const size_t a_base2 = (size_t)(m0 + 64 + r0) * K + cc0;
  const size_t b_base = (size_t)(n0 + r0) * K + cc0;
  const size_t b_base2 = (size_t)(n0 + 64 + r0) * K + cc0;
  bf16* As_d = &As[tid * 8];
  bf16* As_d2 = &As[(256 + tid) * 8];
  bf16* Bs_d = &Bs[tid * 8];
  bf16* Bs_d2 = &Bs[(256 + tid) * 8];

  f32x4 acc[4][4] = {};

  for (int kt = 0; kt < K; kt += 32) {
    gload_lds16(A + a_base + kt, As_d);
    gload_lds16(A + a_base2 + kt, As_d2);
    gload_lds16(Bt + b_base + kt, Bs_d);
    gload_lds16(Bt + b_base2 + kt, Bs_d2);
    __syncthreads();
    bf16x8 af[4], bfr[4];
#pragma unroll
    for (int i = 0; i < 4; ++i) {
      af[i] = *(const bf16x8*)&As[(wm + i * 16 + l15) * 32 + quad * 8];
      bfr[i] = *(const bf16x8*)&Bs[(wn + i * 16 + l15) * 32 + quad * 8];
    }
#pragma unroll
    for (int i = 0; i < 4; ++i)
#pragma unroll
      for (int j = 0; j < 4; ++j)
        acc[i][j] = __builtin_amdgcn_mfma_f32_16x16x32_bf16(af[i], bfr[j],
                                                            acc[i][j], 0, 0, 0);
    __syncthreads();
  }

#pragma unroll
  for (int i = 0; i < 4; ++i) {
#pragma unroll
    for (int r = 0; r < 4; ++r) {
      const int m = m0 + wm + i * 16 + quad * 4 + r;   // C row = quad*4+reg
#pragma unroll
      for (int j = 0; j < 4; ++j) {
        const int n = n0 + wn + j * 16 + l15;          // C col = lane&15
        float v = acc[i][j][r];
        if (EPI == 0) {
          Cb[(size_t)m * N + n] = (bf16)v;
        } else if (EPI == 1) {
          const int b = m >> 11;
          Cf[(size_t)m * N + n] =
              resid[(size_t)m * N + n] + gmod[(size_t)b * MODD + n] * v;
        } else if (EPI == 2) {
          v += bias[n];
          Cb[(size_t)m * N + n] = (bf16)gelu_tanh(v);
        } else {
          v += bias[n];
          const int b = m >> 11;
          Cf[(size_t)m * N + n] =
              resid[(size_t)m * N + n] + gmod[(size_t)b * MODD + n] * v;
        }
      }
    }
  }
}

// ---------------- RMSNorm + RoPE on q,k (in place, one wave = one (token,h)) --
__global__ __launch_bounds__(256) void rope_kernel(
    bf16* __restrict__ qkv, const float* __restrict__ cosb,
    const float* __restrict__ sinb, const float* __restrict__ qw,
    const float* __restrict__ kw) {
  const int wid = threadIdx.x >> 6;
  const int lane = threadIdx.x & 63;
  const int inst = blockIdx.x * 4 + wid;   // 0..B*S*NH-1
  const int h = inst & (NH - 1);
  const int token = inst >> 4;
  const int s = token & (S_LEN - 1);
  const size_t base = (size_t)token * (3 * DIM) + h * HEADD + lane;
  const float cv = cosb[s * HEADD + lane];
  const float sv = sinb[s * HEADD + lane];
  const float sign = (lane < 32) ? -1.0f : 1.0f;
  {
    float xq = (float)qkv[base];
    float ss = xq * xq;
    for (int off = 1; off < 64; off <<= 1) ss += __shfl_xor(ss, off, 64);
    float rn = rsqrtf(ss * (1.0f / HEADD) + 1e-6f);
    float xn = xq * rn * qw[lane];
    float other = __shfl_xor(xn, 32, 64);
    qkv[base] = (bf16)(xn * cv + sign * other * sv);
  }
  {
    float xk = (float)qkv[base + DIM];
    float ss = xk * xk;
    for (int off = 1; off < 64; off <<= 1) ss += __shfl_xor(ss, off, 64);
    float rn = rsqrtf(ss * (1.0f / HEADD) + 1e-6f);
    float xn = xk * rn * kw[lane];
    float other = __shfl_xor(xn, 32, 64);
    qkv[base + DIM] = (bf16)(xn * cv + sign * other * sv);
  }
}

// ---------------- flash attention v2: fixed-shift softmax, pre-transposed V --
// Scores bounded: |q|=|k|=8 after RMS-norm (unit weights) => |s|<=8,
// exp(s)<=3e3, sum<=6.1e6 -> no running max needed. p = exp2(dot*c - 8).
__global__ __launch_bounds__(256) void attn_kernel(
    const bf16* __restrict__ qkv, const bf16* __restrict__ VT,
    bf16* __restrict__ out) {
  __shared__ __align__(16) bf16 Ks[64][72];       // [key][feat]
  __shared__ __align__(16) bf16 Vs[64][72];       // [feat][key] (from VT)
  __shared__ __align__(16) bf16 Ps[4][16][72];    // per-wave P round trip
  const int bh = blockIdx.y;
  const int b = bh >> 4;
  const int h = bh & 15;
  const int q0 = blockIdx.x * 64;
  const int tid = threadIdx.x;
  const int wid = tid >> 6;
  const int lane = tid & 63;
  const int l15 = lane & 15;
  const int quad = lane >> 4;

  const int qrow = q0 + wid * 16 + l15;
  const size_t qbase = (size_t)(b * S_LEN + qrow) * (3 * DIM) + h * HEADD;
  const bf16x8 aq0 = *(const bf16x8*)(qkv + qbase + quad * 8);
  const bf16x8 aq1 = *(const bf16x8*)(qkv + qbase + 32 + quad * 8);

  const int sr = tid >> 3;          // staging row 0..31
  const int sc8 = (tid & 7) * 8;
  const float cexp = 0.125f * 1.44269504f;   // scale * log2(e)

  f32x4 oacc[4] = {};
  float psum[4] = {0.f, 0.f, 0.f, 0.f};

  for (int kt = 0; kt < S_LEN; kt += 64) {
    __syncthreads();   // previous iteration's reads done before restage
#pragma unroll
    for (int rep = 0; rep < 2; ++rep) {
      const int r = rep * 32 + sr;
      *(bf16x8*)&Ks[r][sc8] = *(const bf16x8*)(
          qkv + (size_t)(b * S_LEN + kt + r) * (3 * DIM) + DIM + h * HEADD + sc8);
      *(bf16x8*)&Vs[r][sc8] = *(const bf16x8*)(
          VT + (size_t)(bh * 64 + r) * S_LEN + kt + sc8);
    }
    __syncthreads();

    // S = Q K^T  (16 q-rows x 64 keys per wave)
    f32x4 sc[4] = {};
#pragma unroll
    for (int cc = 0; cc < 4; ++cc) {
      const bf16x8 b0 = *(const bf16x8*)&Ks[cc * 16 + l15][quad * 8];
      const bf16x8 b1 = *(const bf16x8*)&Ks[cc * 16 + l15][32 + quad * 8];
      sc[cc] = __builtin_amdgcn_mfma_f32_16x16x32_bf16(aq0, b0, sc[cc], 0, 0, 0);
      sc[cc] = __builtin_amdgcn_mfma_f32_16x16x32_bf16(aq1, b1, sc[cc], 0, 0, 0);
    }

    // fixed-shift softmax numerator, P -> LDS in C-layout
#pragma unroll
    for (int cc = 0; cc < 4; ++cc) {
#pragma unroll
      for (int r = 0; r < 4; ++r) {
        const float p = __builtin_amdgcn_exp2f(fmaf(sc[cc][r], cexp, -8.0f));
        psum[r] += p;
        Ps[wid][quad * 4 + r][cc * 16 + l15] = (bf16)p;
      }
    }

    // P (A-layout from LDS) @ V
    const bf16x8 pa0 = *(const bf16x8*)&Ps[wid][l15][quad * 8];
    const bf16x8 pa1 = *(const bf16x8*)&Ps[wid][l15][32 + quad * 8];
#pragma unroll
    for (int j = 0; j < 4; ++j) {
      const bf16x8 v0 = *(const bf16x8*)&Vs[j * 16 + l15][quad * 8];
      const bf16x8 v1 = *(const bf16x8*)&Vs[j * 16 + l15][32 + quad * 8];
      oacc[j] = __builtin_amdgcn_mfma_f32_16x16x32_bf16(pa0, v0, oacc[j], 0, 0, 0);
      oacc[j] = __builtin_amdgcn_mfma_f32_16x16x32_bf16(pa1, v1, oacc[j], 0, 0, 0);
    }
  }

  // reduce psum across the 16 lanes holding each row's columns
#pragma unroll
  for (int r = 0; r < 4; ++r) {
    float ps = psum[r];
#pragma unroll
    for (int off = 1; off < 16; off <<= 1) ps += __shfl_xor(ps, off, 64);
    psum[r] = ps;
  }

#pragma unroll
  for (int r = 0; r < 4; ++r) {
    const int m = q0 + wid * 16 + quad * 4 + r;
    const float invl = 1.0f / psum[r];
#pragma unroll
    for (int j = 0; j < 4; ++j)
      out[((size_t)(b * S_LEN + m) * NH + h) * HEADD + j * 16 + l15] =
          (bf16)(oacc[j][r] * invl);
  }
}

// ---------------- launcher ----------------
extern "C" void kernel_launch(void* const* d_in, const int* in_sizes, int n_in,
                              void* d_out, int out_size, void* d_ws,
                              size_t ws_size, hipStream_t stream) {
  const float* x = (const float*)d_in[0];
  const float* cosb = (const float*)d_in[1];
  const float* sinb = (const float*)d_in[2];
  const float* cnd = (const float*)d_in[3];
  const float* norm1_w = (const float*)d_in[4];
  const float* Wqkv = (const float*)d_in[5];
  const float* Wout = (const float*)d_in[6];
  const float* q_norm_w = (const float*)d_in[7];
  const float* k_norm_w = (const float*)d_in[8];
  const float* norm2_w = (const float*)d_in[9];
  const float* W1 = (const float*)d_in[10];
  const float* b1 = (const float*)d_in[11];
  const float* W2 = (const float*)d_in[12];
  const float* b2 = (const float*)d_in[13];
  const float* ada_W = (const float*)d_in[14];
  const float* ada_b = (const float*)d_in[15];
  float* out = (float*)d_out;

  char* p = (char*)d_ws;
  float* mod = (float*)p;   p += (size_t)4 * MODD * 4;        // (4,6144) f32
  bf16* WqkvT = (bf16*)p;   p += (size_t)3072 * 1024 * 2;
  bf16* WoutT = (bf16*)p;   p += (size_t)1024 * 1024 * 2;
  bf16* W1T = (bf16*)p;     p += (size_t)4096 * 1024 * 2;
  bf16* W2T = (bf16*)p;     p += (size_t)1024 * 4096 * 2;
  bf16* XN = (bf16*)p;      p += (size_t)NTOK * DIM * 2;      // ln1 out, reused ln2
  bf16* QKV = (bf16*)p;     p += (size_t)NTOK * 3 * DIM * 2;  // qkv, q/k roped in place
  bf16* ATTN = (bf16*)p;    p += (size_t)NTOK * DIM * 2;
  bf16* Hbuf = (bf16*)p;    p += (size_t)NTOK * DFF * 2;
  bf16* VT = Hbuf;  // alias: VT (16.8 MB) lives in Hbuf (67 MB); Hbuf written
                    // only after attention has consumed VT (stream-serial).

  init_mod_kernel<<<96, 256, 0, stream>>>(ada_b, mod);
  ada_gemm_kernel<<<dim3(24, 8), 256, 0, stream>>>(cnd, ada_W, mod);
  transpose_cast_kernel<<<dim3(96, 32), 256, 0, stream>>>(Wqkv, WqkvT, 1024, 3072);
  transpose_cast_kernel<<<dim3(32, 32), 256, 0, stream>>>(Wout, WoutT, 1024, 1024);
  transpose_cast_kernel<<<dim3(128, 32), 256, 0, stream>>>(W1, W1T, 1024, 4096);
  transpose_cast_kernel<<<dim3(32, 128), 256, 0, stream>>>(W2, W2T, 4096, 1024);
  ln_mod_kernel<<<NTOK, 256, 0, stream>>>(x, norm1_w, mod, 0, 1024, XN);
  gemm_bt<0><<<dim3(24, 64), 256, 0, stream>>>(XN, WqkvT, QKV, nullptr, nullptr,
                                               nullptr, nullptr, NTOK, 3072, 1024);
  rope_kernel<<<NTOK * NH / 4, 256, 0, stream>>>(QKV, cosb, sinb, q_norm_w, k_norm_w);
  vtrans_kernel<<<dim3(32, 64), 256, 0, stream>>>(QKV, VT);
  attn_kernel<<<dim3(32, 64), 256, 0, stream>>>(QKV, VT, ATTN);
  gemm_bt<1><<<dim3(8, 64), 256, 0, stream>>>(ATTN, WoutT, nullptr, out, nullptr,
                                              mod + 2 * 1024, x, NTOK, 1024, 1024);
  ln_mod_kernel<<<NTOK, 256, 0, stream>>>(out, norm2_w, mod, 3 * 1024, 4 * 1024, XN);
  gemm_bt<2><<<dim3(32, 64), 256, 0, stream>>>(XN, W1T, Hbuf, nullptr, b1, nullptr,
                                               nullptr, NTOK, DFF, 1024);
  gemm_bt<3><<<dim3(8, 64), 256, 0, stream>>>(Hbuf, W2T, nullptr, out, b2,
                                              mod + 5 * 1024, out, NTOK, 1024, DFF);
  (void)in_sizes; (void)n_in; (void)out_size; (void)ws_size;
}

// Round 3
// 684.193 us; speedup vs baseline: 1.2476x; 1.0568x over previous
//
#include <hip/hip_runtime.h>
#include <hip/hip_bf16.h>
#include <math.h>

typedef __bf16 bf16;
typedef __bf16 bf16x8 __attribute__((ext_vector_type(8)));
typedef __bf16 bf16x4 __attribute__((ext_vector_type(4)));
typedef float f32x4 __attribute__((ext_vector_type(4)));

#define S_LEN 2048
#define NTOK 8192          // B*S
#define DIM 1024
#define NH 16
#define HEADD 64
#define DFF 4096
#define MODD 6144          // 6*D

// async global->LDS, 16B per lane; LDS side must be wave-uniform base + lane*16
__device__ __forceinline__ void gload_lds16(const bf16* g, bf16* l) {
  __builtin_amdgcn_global_load_lds(
      (const __attribute__((address_space(1))) void*)g,
      (__attribute__((address_space(3))) void*)l, 16, 0, 0);
}

__device__ __forceinline__ float gelu_tanh(float x) {
  float inner = 0.7978845608028654f * (x + 0.044715f * x * x * x);
  return 0.5f * x * (1.0f + tanhf(inner));
}

// ---------------- mod = c @ ada_W + ada_b ----------------
__global__ __launch_bounds__(256) void init_mod_kernel(
    const float* __restrict__ ada_b, float* __restrict__ mod) {
  int i = blockIdx.x * 256 + threadIdx.x;   // 0..24575
  mod[i] = ada_b[i % MODD];
}

__global__ __launch_bounds__(256) void ada_gemm_kernel(
    const float* __restrict__ cnd, const float* __restrict__ W,
    float* __restrict__ mod) {
  int n = blockIdx.x * 256 + threadIdx.x;   // 0..6143
  int k0 = blockIdx.y * 128;
  float a0 = 0.f, a1 = 0.f, a2 = 0.f, a3 = 0.f;
  for (int k = k0; k < k0 + 128; ++k) {
    float w = W[(size_t)k * MODD + n];
    a0 = fmaf(cnd[k], w, a0);
    a1 = fmaf(cnd[1024 + k], w, a1);
    a2 = fmaf(cnd[2048 + k], w, a2);
    a3 = fmaf(cnd[3072 + k], w, a3);
  }
  atomicAdd(&mod[n], a0);
  atomicAdd(&mod[MODD + n], a1);
  atomicAdd(&mod[2 * MODD + n], a2);
  atomicAdd(&mod[3 * MODD + n], a3);
}

// ---------------- W (K,N) fp32 -> Wt (N,K) bf16 ----------------
__global__ __launch_bounds__(256) void transpose_cast_kernel(
    const float* __restrict__ W, bf16* __restrict__ Wt, int K, int N) {
  __shared__ float tile[32][33];
  int n0 = blockIdx.x * 32, k0 = blockIdx.y * 32;
  int r = threadIdx.x >> 3;
  int c4 = (threadIdx.x & 7) * 4;
  float4 v = *(const float4*)&W[(size_t)(k0 + r) * N + n0 + c4];
  tile[r][c4 + 0] = v.x; tile[r][c4 + 1] = v.y;
  tile[r][c4 + 2] = v.z; tile[r][c4 + 3] = v.w;
  __syncthreads();
  bf16x4 o;
  o[0] = (bf16)tile[c4 + 0][r];
  o[1] = (bf16)tile[c4 + 1][r];
  o[2] = (bf16)tile[c4 + 2][r];
  o[3] = (bf16)tile[c4 + 3][r];
  *(bf16x4*)&Wt[(size_t)(n0 + r) * K + k0 + c4] = o;
}

// ---------------- V part of qkv -> VT[b][h][d][s] ----------------
__global__ __launch_bounds__(256) void vtrans_kernel(
    const bf16* __restrict__ qkv, bf16* __restrict__ VT) {
  __shared__ __align__(16) bf16 t[64][72];
  const int bh = blockIdx.y;
  const int b = bh >> 4, h = bh & 15;
  const int s0 = blockIdx.x * 64;
  const int tid = threadIdx.x;
  {
    const int r = tid >> 2;
    const int c = (tid & 3) * 16;
    const bf16* src =
        qkv + (size_t)(b * S_LEN + s0 + r) * 3072 + 2048 + h * 64 + c;
    *(bf16x8*)&t[r][c] = *(const bf16x8*)src;
    *(bf16x8*)&t[r][c + 8] = *(const bf16x8*)(src + 8);
  }
  __syncthreads();
  {
    const int d = tid & 63;
    const int sc = (tid >> 6) * 16;
    bf16x8 o0, o1;
#pragma unroll
    for (int j = 0; j < 8; ++j) o0[j] = t[sc + j][d];
#pragma unroll
    for (int j = 0; j < 8; ++j) o1[j] = t[sc + 8 + j][d];
    bf16* dst = VT + (size_t)(bh * 64 + d) * S_LEN + s0 + sc;
    *(bf16x8*)dst = o0;
    *(bf16x8*)(dst + 8) = o1;
  }
}

// ---------------- LayerNorm + adaLN modulate -> bf16 ----------------
__global__ __launch_bounds__(256) void ln_mod_kernel(
    const float* __restrict__ x, const float* __restrict__ w,
    const float* __restrict__ mod, int sh_off, int sc_off,
    bf16* __restrict__ out) {
  __shared__ float red[8];
  const int row = blockIdx.x;
  const int b = row >> 11;          // row / 2048
  const int tid = threadIdx.x;
  const float4 v = ((const float4*)(x + (size_t)row * DIM))[tid];
  float s1 = v.x + v.y + v.z + v.w;
  float s2 = v.x * v.x + v.y * v.y + v.z * v.z + v.w * v.w;
  for (int off = 32; off > 0; off >>= 1) {
    s1 += __shfl_down(s1, off, 64);
    s2 += __shfl_down(s2, off, 64);
  }
  const int wid = tid >> 6;
  if ((tid & 63) == 0) { red[wid] = s1; red[4 + wid] = s2; }
  __syncthreads();
  s1 = red[0] + red[1] + red[2] + red[3];
  s2 = red[4] + red[5] + red[6] + red[7];
  const float mu = s1 * (1.0f / DIM);
  const float inv = rsqrtf(s2 * (1.0f / DIM) - mu * mu + 1e-5f);
  const int c = tid * 4;
  const float* mb = mod + (size_t)b * MODD;
  float xs[4] = {v.x, v.y, v.z, v.w};
  bf16x4 o;
#pragma unroll
  for (int j = 0; j < 4; ++j)
    o[j] = (bf16)(((xs[j] - mu) * inv) * w[c + j] * (1.0f + mb[sc_off + c + j]) +
                  mb[sh_off + c + j]);
  *(bf16x4*)(out + (size_t)row * DIM + c) = o;
}

// ---------------- bf16 MFMA GEMM, C = A(M,K) @ Bt(N,K)^T, fused epilogues ----
// K-step 64 via two BK=32 buffer pairs under one barrier pair (halves drains).
template <int EPI>
__global__ __launch_bounds__(256) void gemm_bt(
    const bf16* __restrict__ A, const bf16* __restrict__ Bt,
    bf16* __restrict__ Cb, float* __restrict__ Cf,
    const float* __restrict__ bias, const float* __restrict__ gmod,
    const float* __restrict__ resid, int M, int N, int K) {
  __shared__ __align__(16) bf16 As[2][128 * 32];
  __shared__ __align__(16) bf16 Bs[2][128 * 32];
  const int tid = threadIdx.x;
  const int wid = tid >> 6;
  const int lane = tid & 63;
  const int l15 = lane & 15;
  const int quad = lane >> 4;
  const int m0 = blockIdx.y * 128;
  const int n0 = blockIdx.x * 128;
  const int wm = (wid & 1) * 64;
  const int wn = (wid >> 1) * 64;

  const int r0 = tid >> 2;           // 0..63
  const int cc0 = (tid & 3) * 8;     // k-chunk offset in elements
  const size_t a_base = (size_t)(m0 + r0) * K + cc0;
  const size_t a_base2 = (size_t)(m0 + 64 + r0) * K + cc0;
  const size_t b_base = (size_t)(n0 + r0) * K + cc0;
  const size_t b_base2 = (size_t)(n0 + 64 + r0) * K + cc0;

  f32x4 acc[4][4] = {};

  for (int kt = 0; kt < K; kt += 64) {
    gload_lds16(A + a_base + kt, &As[0][tid * 8]);
    gload_lds16(A + a_base2 + kt, &As[0][(256 + tid) * 8]);
    gload_lds16(Bt + b_base + kt, &Bs[0][tid * 8]);
    gload_lds16(Bt + b_base2 + kt, &Bs[0][(256 + tid) * 8]);
    gload_lds16(A + a_base + kt + 32, &As[1][tid * 8]);
    gload_lds16(A + a_base2 + kt + 32, &As[1][(256 + tid) * 8]);
    gload_lds16(Bt + b_base + kt + 32, &Bs[1][tid * 8]);
    gload_lds16(Bt + b_base2 + kt + 32, &Bs[1][(256 + tid) * 8]);
    __syncthreads();
#pragma unroll
    for (int half = 0; half < 2; ++half) {
      bf16x8 af[4], bfr[4];
#pragma unroll
      for (int i = 0; i < 4; ++i) {
        af[i] = *(const bf16x8*)&As[half][(wm + i * 16 + l15) * 32 + quad * 8];
        bfr[i] = *(const bf16x8*)&Bs[half][(wn + i * 16 + l15) * 32 + quad * 8];
      }
#pragma unroll
      for (int i = 0; i < 4; ++i)
#pragma unroll
        for (int j = 0; j < 4; ++j)
          acc[i][j] = __builtin_amdgcn_mfma_f32_16x16x32_bf16(af[i], bfr[j],
                                                              acc[i][j], 0, 0, 0);
    }
    __syncthreads();
  }

#pragma unroll
  for (int i = 0; i < 4; ++i) {
#pragma unroll
    for (int r = 0; r < 4; ++r) {
      const int m = m0 + wm + i * 16 + quad * 4 + r;   // C row = quad*4+reg
#pragma unroll
      for (int j = 0; j < 4; ++j) {
        const int n = n0 + wn + j * 16 + l15;          // C col = lane&15
        float v = acc[i][j][r];
        if (EPI == 0) {
          Cb[(size_t)m * N + n] = (bf16)v;
        } else if (EPI == 1) {
          const int b = m >> 11;
          Cf[(size_t)m * N + n] =
              resid[(size_t)m * N + n] + gmod[(size_t)b * MODD + n] * v;
        } else if (EPI == 2) {
          v += bias[n];
          Cb[(size_t)m * N + n] = (bf16)gelu_tanh(v);
        } else {
          v += bias[n];
          const int b = m >> 11;
          Cf[(size_t)m * N + n] =
              resid[(size_t)m * N + n] + gmod[(size_t)b * MODD + n] * v;
        }
      }
    }
  }
}

// ---------------- RMSNorm + RoPE on q,k (in place, one wave = one (token,h)) --
__global__ __launch_bounds__(256) void rope_kernel(
    bf16* __restrict__ qkv, const float* __restrict__ cosb,
    const float* __restrict__ sinb, const float* __restrict__ qw,
    const float* __restrict__ kw) {
  const int wid = threadIdx.x >> 6;
  const int lane = threadIdx.x & 63;
  const int inst = blockIdx.x * 4 + wid;   // 0..B*S*NH-1
  const int h = inst & (NH - 1);
  const int token = inst >> 4;
  const int s = token & (S_LEN - 1);
  const size_t base = (size_t)token * (3 * DIM) + h * HEADD + lane;
  const float cv = cosb[s * HEADD + lane];
  const float sv = sinb[s * HEADD + lane];
  const float sign = (lane < 32) ? -1.0f : 1.0f;
  {
    float xq = (float)qkv[base];
    float ss = xq * xq;
    for (int off = 1; off < 64; off <<= 1) ss += __shfl_xor(ss, off, 64);
    float rn = rsqrtf(ss * (1.0f / HEADD) + 1e-6f);
    float xn = xq * rn * qw[lane];
    float other = __shfl_xor(xn, 32, 64);
    qkv[base] = (bf16)(xn * cv + sign * other * sv);
  }
  {
    float xk = (float)qkv[base + DIM];
    float ss = xk * xk;
    for (int off = 1; off < 64; off <<= 1) ss += __shfl_xor(ss, off, 64);
    float rn = rsqrtf(ss * (1.0f / HEADD) + 1e-6f);
    float xn = xk * rn * kw[lane];
    float other = __shfl_xor(xn, 32, 64);
    qkv[base + DIM] = (bf16)(xn * cv + sign * other * sv);
  }
}

// ---------------- flash attention v3: 32 q-rows/wave, 128 q-rows/block --------
// Scores bounded: |q|=|k|=8 after RMS-norm (unit weights) => |s|<=8 -> fixed
// shift exp2(s*c - 8), no running max. K/V tile LDS reads amortized over 2
// q-subtiles per wave (LDS-throughput was the R2 bottleneck).
__global__ __launch_bounds__(256) void attn_kernel(
    const bf16* __restrict__ qkv, const bf16* __restrict__ VT,
    bf16* __restrict__ out) {
  __shared__ __align__(16) bf16 Ks[64][72];       // [key][feat]
  __shared__ __align__(16) bf16 Vs[64][72];       // [feat][key] (from VT)
  __shared__ __align__(16) bf16 Ps[4][32][72];    // per-wave P round trip
  const int bh = blockIdx.y;
  const int b = bh >> 4;
  const int h = bh & 15;
  const int q0 = blockIdx.x * 128;
  const int tid = threadIdx.x;
  const int wid = tid >> 6;
  const int lane = tid & 63;
  const int l15 = lane & 15;
  const int quad = lane >> 4;

  bf16x8 aq[2][2];
#pragma unroll
  for (int i = 0; i < 2; ++i) {
    const int qrow = q0 + wid * 32 + i * 16 + l15;
    const size_t qbase = (size_t)(b * S_LEN + qrow) * (3 * DIM) + h * HEADD;
    aq[i][0] = *(const bf16x8*)(qkv + qbase + quad * 8);
    aq[i][1] = *(const bf16x8*)(qkv + qbase + 32 + quad * 8);
  }

  const int sr = tid >> 3;          // staging row 0..31
  const int sc8 = (tid & 7) * 8;
  const float cexp = 0.125f * 1.44269504f;   // scale * log2(e)

  f32x4 oacc[2][4] = {};
  float psum[2][4] = {{0.f, 0.f, 0.f, 0.f}, {0.f, 0.f, 0.f, 0.f}};

  for (int kt = 0; kt < S_LEN; kt += 64) {
    __syncthreads();   // previous iteration's reads done before restage
#pragma unroll
    for (int rep = 0; rep < 2; ++rep) {
      const int r = rep * 32 + sr;
      *(bf16x8*)&Ks[r][sc8] = *(const bf16x8*)(
          qkv + (size_t)(b * S_LEN + kt + r) * (3 * DIM) + DIM + h * HEADD + sc8);
      *(bf16x8*)&Vs[r][sc8] = *(const bf16x8*)(
          VT + (size_t)(bh * 64 + r) * S_LEN + kt + sc8);
    }
    __syncthreads();

    // S = Q K^T  (2 x 16 q-rows x 64 keys per wave; Ks frags shared across i)
    f32x4 sc[2][4] = {};
#pragma unroll
    for (int cc = 0; cc < 4; ++cc) {
      const bf16x8 b0 = *(const bf16x8*)&Ks[cc * 16 + l15][quad * 8];
      const bf16x8 b1 = *(const bf16x8*)&Ks[cc * 16 + l15][32 + quad * 8];
#pragma unroll
      for (int i = 0; i < 2; ++i) {
        sc[i][cc] = __builtin_amdgcn_mfma_f32_16x16x32_bf16(aq[i][0], b0, sc[i][cc], 0, 0, 0);
        sc[i][cc] = __builtin_amdgcn_mfma_f32_16x16x32_bf16(aq[i][1], b1, sc[i][cc], 0, 0, 0);
      }
    }

    // fixed-shift softmax numerator, P -> LDS in C-layout
#pragma unroll
    for (int i = 0; i < 2; ++i)
#pragma unroll
      for (int cc = 0; cc < 4; ++cc)
#pragma unroll
        for (int r = 0; r < 4; ++r) {
          const float p = __builtin_amdgcn_exp2f(fmaf(sc[i][cc][r], cexp, -8.0f));
          psum[i][r] += p;
          Ps[wid][i * 16 + quad * 4 + r][cc * 16 + l15] = (bf16)p;
        }

    // P (A-layout from LDS) @ V  (Vs frags shared across i)
    bf16x8 pa[2][2];
#pragma unroll
    for (int i = 0; i < 2; ++i) {
      pa[i][0] = *(const bf16x8*)&Ps[wid][i * 16 + l15][quad * 8];
      pa[i][1] = *(const bf16x8*)&Ps[wid][i * 16 + l15][32 + quad * 8];
    }
#pragma unroll
    for (int j = 0; j < 4; ++j) {
      const bf16x8 v0 = *(const bf16x8*)&Vs[j * 16 + l15][quad * 8];
      const bf16x8 v1 = *(const bf16x8*)&Vs[j * 16 + l15][32 + quad * 8];
#pragma unroll
      for (int i = 0; i < 2; ++i) {
        oacc[i][j] = __builtin_amdgcn_mfma_f32_16x16x32_bf16(pa[i][0], v0, oacc[i][j], 0, 0, 0);
        oacc[i][j] = __builtin_amdgcn_mfma_f32_16x16x32_bf16(pa[i][1], v1, oacc[i][j], 0, 0, 0);
      }
    }
  }

  // reduce psum across the 16 lanes holding each row's columns; write out
#pragma unroll
  for (int i = 0; i < 2; ++i)
#pragma unroll
    for (int r = 0; r < 4; ++r) {
      float ps = psum[i][r];
#pragma unroll
      for (int off = 1; off < 16; off <<= 1) ps += __shfl_xor(ps, off, 64);
      const int m = q0 + wid * 32 + i * 16 + quad * 4 + r;
      const float invl = 1.0f / ps;
#pragma unroll
      for (int j = 0; j < 4; ++j)
        out[((size_t)(b * S_LEN + m) * NH + h) * HEADD + j * 16 + l15] =
            (bf16)(oacc[i][j][r] * invl);
    }
}

// ---------------- launcher ----------------
extern "C" void kernel_launch(void* const* d_in, const int* in_sizes, int n_in,
                              void* d_out, int out_size, void* d_ws,
                              size_t ws_size, hipStream_t stream) {
  const float* x = (const float*)d_in[0];
  const float* cosb = (const float*)d_in[1];
  const float* sinb = (const float*)d_in[2];
  const float* cnd = (const float*)d_in[3];
  const float* norm1_w = (const float*)d_in[4];
  const float* Wqkv = (const float*)d_in[5];
  const float* Wout = (const float*)d_in[6];
  const float* q_norm_w = (const float*)d_in[7];
  const float* k_norm_w = (const float*)d_in[8];
  const float* norm2_w = (const float*)d_in[9];
  const float* W1 = (const float*)d_in[10];
  const float* b1 = (const float*)d_in[11];
  const float* W2 = (const float*)d_in[12];
  const float* b2 = (const float*)d_in[13];
  const float* ada_W = (const float*)d_in[14];
  const float* ada_b = (const float*)d_in[15];
  float* out = (float*)d_out;

  char* p = (char*)d_ws;
  float* mod = (float*)p;   p += (size_t)4 * MODD * 4;        // (4,6144) f32
  bf16* WqkvT = (bf16*)p;   p += (size_t)3072 * 1024 * 2;
  bf16* WoutT = (bf16*)p;   p += (size_t)1024 * 1024 * 2;
  bf16* W1T = (bf16*)p;     p += (size_t)4096 * 1024 * 2;
  bf16* W2T = (bf16*)p;     p += (size_t)1024 * 4096 * 2;
  bf16* XN = (bf16*)p;      p += (size_t)NTOK * DIM * 2;      // ln1 out, reused ln2
  bf16* QKV = (bf16*)p;     p += (size_t)NTOK * 3 * DIM * 2;  // qkv, q/k roped in place
  bf16* ATTN = (bf16*)p;    p += (size_t)NTOK * DIM * 2;
  bf16* Hbuf = (bf16*)p;    p += (size_t)NTOK * DFF * 2;
  bf16* VT = Hbuf;  // alias: VT (16.8 MB) lives in Hbuf (67 MB); Hbuf written
                    // only after attention has consumed VT (stream-serial).

  init_mod_kernel<<<96, 256, 0, stream>>>(ada_b, mod);
  ada_gemm_kernel<<<dim3(24, 8), 256, 0, stream>>>(cnd, ada_W, mod);
  transpose_cast_kernel<<<dim3(96, 32), 256, 0, stream>>>(Wqkv, WqkvT, 1024, 3072);
  transpose_cast_kernel<<<dim3(32, 32), 256, 0, stream>>>(Wout, WoutT, 1024, 1024);
  transpose_cast_kernel<<<dim3(128, 32), 256, 0, stream>>>(W1, W1T, 1024, 4096);
  transpose_cast_kernel<<<dim3(32, 128), 256, 0, stream>>>(W2, W2T, 4096, 1024);
  ln_mod_kernel<<<NTOK, 256, 0, stream>>>(x, norm1_w, mod, 0, 1024, XN);
  gemm_bt<0><<<dim3(24, 64), 256, 0, stream>>>(XN, WqkvT, QKV, nullptr, nullptr,
                                               nullptr, nullptr, NTOK, 3072, 1024);
  rope_kernel<<<NTOK * NH / 4, 256, 0, stream>>>(QKV, cosb, sinb, q_norm_w, k_norm_w);
  vtrans_kernel<<<dim3(32, 64), 256, 0, stream>>>(QKV, VT);
  attn_kernel<<<dim3(16, 64), 256, 0, stream>>>(QKV, VT, ATTN);
  gemm_bt<1><<<dim3(8, 64), 256, 0, stream>>>(ATTN, WoutT, nullptr, out, nullptr,
                                              mod + 2 * 1024, x, NTOK, 1024, 1024);
  ln_mod_kernel<<<NTOK, 256, 0, stream>>>(out, norm2_w, mod, 3 * 1024, 4 * 1024, XN);
  gemm_bt<2><<<dim3(32, 64), 256, 0, stream>>>(XN, W1T, Hbuf, nullptr, b1, nullptr,
                                               nullptr, NTOK, DFF, 1024);
  gemm_bt<3><<<dim3(8, 64), 256, 0, stream>>>(Hbuf, W2T, nullptr, out, b2,
                                              mod + 5 * 1024, out, NTOK, 1024, DFF);
  (void)in_sizes; (void)n_in; (void)out_size; (void)ws_size;
}

// Round 4
// 681.433 us; speedup vs baseline: 1.2526x; 1.0040x over previous
//
#include <hip/hip_runtime.h>
#include <hip/hip_bf16.h>
#include <math.h>

typedef __bf16 bf16;
typedef __bf16 bf16x8 __attribute__((ext_vector_type(8)));
typedef __bf16 bf16x4 __attribute__((ext_vector_type(4)));
typedef float f32x4 __attribute__((ext_vector_type(4)));
typedef short s16x4 __attribute__((ext_vector_type(4)));

#define S_LEN 2048
#define NTOK 8192          // B*S
#define DIM 1024
#define NH 16
#define HEADD 64
#define DFF 4096
#define MODD 6144          // 6*D

// async global->LDS, 16B per lane; LDS side must be wave-uniform base + lane*16
__device__ __forceinline__ void gload_lds16(const bf16* g, bf16* l) {
  __builtin_amdgcn_global_load_lds(
      (const __attribute__((address_space(1))) void*)g,
      (__attribute__((address_space(3))) void*)l, 16, 0, 0);
}

__device__ __forceinline__ float gelu_tanh(float x) {
  float inner = 0.7978845608028654f * (x + 0.044715f * x * x * x);
  return 0.5f * x * (1.0f + tanhf(inner));
}

// ---------------- mod = c @ ada_W + ada_b ----------------
__global__ __launch_bounds__(256) void init_mod_kernel(
    const float* __restrict__ ada_b, float* __restrict__ mod) {
  int i = blockIdx.x * 256 + threadIdx.x;   // 0..24575
  mod[i] = ada_b[i % MODD];
}

__global__ __launch_bounds__(256) void ada_gemm_kernel(
    const float* __restrict__ cnd, const float* __restrict__ W,
    float* __restrict__ mod) {
  int n = blockIdx.x * 256 + threadIdx.x;   // 0..6143
  int k0 = blockIdx.y * 128;
  float a0 = 0.f, a1 = 0.f, a2 = 0.f, a3 = 0.f;
  for (int k = k0; k < k0 + 128; ++k) {
    float w = W[(size_t)k * MODD + n];
    a0 = fmaf(cnd[k], w, a0);
    a1 = fmaf(cnd[1024 + k], w, a1);
    a2 = fmaf(cnd[2048 + k], w, a2);
    a3 = fmaf(cnd[3072 + k], w, a3);
  }
  atomicAdd(&mod[n], a0);
  atomicAdd(&mod[MODD + n], a1);
  atomicAdd(&mod[2 * MODD + n], a2);
  atomicAdd(&mod[3 * MODD + n], a3);
}

// ---------------- W (K,N) fp32 -> Wt (N,K) bf16 ----------------
__global__ __launch_bounds__(256) void transpose_cast_kernel(
    const float* __restrict__ W, bf16* __restrict__ Wt, int K, int N) {
  __shared__ float tile[32][33];
  int n0 = blockIdx.x * 32, k0 = blockIdx.y * 32;
  int r = threadIdx.x >> 3;
  int c4 = (threadIdx.x & 7) * 4;
  float4 v = *(const float4*)&W[(size_t)(k0 + r) * N + n0 + c4];
  tile[r][c4 + 0] = v.x; tile[r][c4 + 1] = v.y;
  tile[r][c4 + 2] = v.z; tile[r][c4 + 3] = v.w;
  __syncthreads();
  bf16x4 o;
  o[0] = (bf16)tile[c4 + 0][r];
  o[1] = (bf16)tile[c4 + 1][r];
  o[2] = (bf16)tile[c4 + 2][r];
  o[3] = (bf16)tile[c4 + 3][r];
  *(bf16x4*)&Wt[(size_t)(n0 + r) * K + k0 + c4] = o;
}

// ---------------- V part of qkv -> VT[b][h][d][s] ----------------
__global__ __launch_bounds__(256) void vtrans_kernel(
    const bf16* __restrict__ qkv, bf16* __restrict__ VT) {
  __shared__ __align__(16) bf16 t[64][72];
  const int bh = blockIdx.y;
  const int b = bh >> 4, h = bh & 15;
  const int s0 = blockIdx.x * 64;
  const int tid = threadIdx.x;
  {
    const int r = tid >> 2;
    const int c = (tid & 3) * 16;
    const bf16* src =
        qkv + (size_t)(b * S_LEN + s0 + r) * 3072 + 2048 + h * 64 + c;
    *(bf16x8*)&t[r][c] = *(const bf16x8*)src;
    *(bf16x8*)&t[r][c + 8] = *(const bf16x8*)(src + 8);
  }
  __syncthreads();
  {
    const int d = tid & 63;
    const int sc = (tid >> 6) * 16;
    bf16x8 o0, o1;
#pragma unroll
    for (int j = 0; j < 8; ++j) o0[j] = t[sc + j][d];
#pragma unroll
    for (int j = 0; j < 8; ++j) o1[j] = t[sc + 8 + j][d];
    bf16* dst = VT + (size_t)(bh * 64 + d) * S_LEN + s0 + sc;
    *(bf16x8*)dst = o0;
    *(bf16x8*)(dst + 8) = o1;
  }
}

// ---------------- LayerNorm + adaLN modulate -> bf16 ----------------
__global__ __launch_bounds__(256) void ln_mod_kernel(
    const float* __restrict__ x, const float* __restrict__ w,
    const float* __restrict__ mod, int sh_off, int sc_off,
    bf16* __restrict__ out) {
  __shared__ float red[8];
  const int row = blockIdx.x;
  const int b = row >> 11;          // row / 2048
  const int tid = threadIdx.x;
  const float4 v = ((const float4*)(x + (size_t)row * DIM))[tid];
  float s1 = v.x + v.y + v.z + v.w;
  float s2 = v.x * v.x + v.y * v.y + v.z * v.z + v.w * v.w;
  for (int off = 32; off > 0; off >>= 1) {
    s1 += __shfl_down(s1, off, 64);
    s2 += __shfl_down(s2, off, 64);
  }
  const int wid = tid >> 6;
  if ((tid & 63) == 0) { red[wid] = s1; red[4 + wid] = s2; }
  __syncthreads();
  s1 = red[0] + red[1] + red[2] + red[3];
  s2 = red[4] + red[5] + red[6] + red[7];
  const float mu = s1 * (1.0f / DIM);
  const float inv = rsqrtf(s2 * (1.0f / DIM) - mu * mu + 1e-5f);
  const int c = tid * 4;
  const float* mb = mod + (size_t)b * MODD;
  float xs[4] = {v.x, v.y, v.z, v.w};
  bf16x4 o;
#pragma unroll
  for (int j = 0; j < 4; ++j)
    o[j] = (bf16)(((xs[j] - mu) * inv) * w[c + j] * (1.0f + mb[sc_off + c + j]) +
                  mb[sh_off + c + j]);
  *(bf16x4*)(out + (size_t)row * DIM + c) = o;
}

// ---------------- bf16 MFMA GEMM, C = A(M,K) @ Bt(N,K)^T, fused epilogues ----
// K-step 64 via two BK=32 buffer pairs under one barrier pair (halves drains).
template <int EPI>
__global__ __launch_bounds__(256) void gemm_bt(
    const bf16* __restrict__ A, const bf16* __restrict__ Bt,
    bf16* __restrict__ Cb, float* __restrict__ Cf,
    const float* __restrict__ bias, const float* __restrict__ gmod,
    const float* __restrict__ resid, int M, int N, int K) {
  __shared__ __align__(16) bf16 As[2][128 * 32];
  __shared__ __align__(16) bf16 Bs[2][128 * 32];
  const int tid = threadIdx.x;
  const int wid = tid >> 6;
  const int lane = tid & 63;
  const int l15 = lane & 15;
  const int quad = lane >> 4;
  const int m0 = blockIdx.y * 128;
  const int n0 = blockIdx.x * 128;
  const int wm = (wid & 1) * 64;
  const int wn = (wid >> 1) * 64;

  const int r0 = tid >> 2;           // 0..63
  const int cc0 = (tid & 3) * 8;     // k-chunk offset in elements
  const size_t a_base = (size_t)(m0 + r0) * K + cc0;
  const size_t a_base2 = (size_t)(m0 + 64 + r0) * K + cc0;
  const size_t b_base = (size_t)(n0 + r0) * K + cc0;
  const size_t b_base2 = (size_t)(n0 + 64 + r0) * K + cc0;

  f32x4 acc[4][4] = {};

  for (int kt = 0; kt < K; kt += 64) {
    gload_lds16(A + a_base + kt, &As[0][tid * 8]);
    gload_lds16(A + a_base2 + kt, &As[0][(256 + tid) * 8]);
    gload_lds16(Bt + b_base + kt, &Bs[0][tid * 8]);
    gload_lds16(Bt + b_base2 + kt, &Bs[0][(256 + tid) * 8]);
    gload_lds16(A + a_base + kt + 32, &As[1][tid * 8]);
    gload_lds16(A + a_base2 + kt + 32, &As[1][(256 + tid) * 8]);
    gload_lds16(Bt + b_base + kt + 32, &Bs[1][tid * 8]);
    gload_lds16(Bt + b_base2 + kt + 32, &Bs[1][(256 + tid) * 8]);
    __syncthreads();
#pragma unroll
    for (int half = 0; half < 2; ++half) {
      bf16x8 af[4], bfr[4];
#pragma unroll
      for (int i = 0; i < 4; ++i) {
        af[i] = *(const bf16x8*)&As[half][(wm + i * 16 + l15) * 32 + quad * 8];
        bfr[i] = *(const bf16x8*)&Bs[half][(wn + i * 16 + l15) * 32 + quad * 8];
      }
#pragma unroll
      for (int i = 0; i < 4; ++i)
#pragma unroll
        for (int j = 0; j < 4; ++j)
          acc[i][j] = __builtin_amdgcn_mfma_f32_16x16x32_bf16(af[i], bfr[j],
                                                              acc[i][j], 0, 0, 0);
    }
    __syncthreads();
  }

#pragma unroll
  for (int i = 0; i < 4; ++i) {
#pragma unroll
    for (int r = 0; r < 4; ++r) {
      const int m = m0 + wm + i * 16 + quad * 4 + r;   // C row = quad*4+reg
#pragma unroll
      for (int j = 0; j < 4; ++j) {
        const int n = n0 + wn + j * 16 + l15;          // C col = lane&15
        float v = acc[i][j][r];
        if (EPI == 0) {
          Cb[(size_t)m * N + n] = (bf16)v;
        } else if (EPI == 1) {
          const int b = m >> 11;
          Cf[(size_t)m * N + n] =
              resid[(size_t)m * N + n] + gmod[(size_t)b * MODD + n] * v;
        } else if (EPI == 2) {
          v += bias[n];
          Cb[(size_t)m * N + n] = (bf16)gelu_tanh(v);
        } else {
          v += bias[n];
          const int b = m >> 11;
          Cf[(size_t)m * N + n] =
              resid[(size_t)m * N + n] + gmod[(size_t)b * MODD + n] * v;
        }
      }
    }
  }
}

// ---------------- RMSNorm + RoPE on q,k (in place, one wave = one (token,h)) --
__global__ __launch_bounds__(256) void rope_kernel(
    bf16* __restrict__ qkv, const float* __restrict__ cosb,
    const float* __restrict__ sinb, const float* __restrict__ qw,
    const float* __restrict__ kw) {
  const int wid = threadIdx.x >> 6;
  const int lane = threadIdx.x & 63;
  const int inst = blockIdx.x * 4 + wid;   // 0..B*S*NH-1
  const int h = inst & (NH - 1);
  const int token = inst >> 4;
  const int s = token & (S_LEN - 1);
  const size_t base = (size_t)token * (3 * DIM) + h * HEADD + lane;
  const float cv = cosb[s * HEADD + lane];
  const float sv = sinb[s * HEADD + lane];
  const float sign = (lane < 32) ? -1.0f : 1.0f;
  {
    float xq = (float)qkv[base];
    float ss = xq * xq;
    for (int off = 1; off < 64; off <<= 1) ss += __shfl_xor(ss, off, 64);
    float rn = rsqrtf(ss * (1.0f / HEADD) + 1e-6f);
    float xn = xq * rn * qw[lane];
    float other = __shfl_xor(xn, 32, 64);
    qkv[base] = (bf16)(xn * cv + sign * other * sv);
  }
  {
    float xk = (float)qkv[base + DIM];
    float ss = xk * xk;
    for (int off = 1; off < 64; off <<= 1) ss += __shfl_xor(ss, off, 64);
    float rn = rsqrtf(ss * (1.0f / HEADD) + 1e-6f);
    float xn = xk * rn * kw[lane];
    float other = __shfl_xor(xn, 32, 64);
    qkv[base + DIM] = (bf16)(xn * cv + sign * other * sv);
  }
}

// ---------------- flash attention v4: register-P via S^T, swizzled LDS -------
// S^T = K·Q^T via 16x16x32 MFMA; its C-layout (qrow=lane&15, key=quad*4+reg)
// equals the A-operand layout of 16x16x16 MFMA, so P=exp(S) stays in registers
// for P·V (no LDS round trip). K/V tiles in XOR-swizzled stride-64 LDS: both
// staging writes and all frag reads are at the bank floor (zero conflicts).
// Scores bounded (|q|=|k|=8 post-RMS-norm) -> fixed-shift exp2(s*c - 8).
__global__ __launch_bounds__(256) void attn_kernel(
    const bf16* __restrict__ qkv, const bf16* __restrict__ VT,
    bf16* __restrict__ out) {
  __shared__ __align__(16) bf16 Ks[4096];   // [key][feat], chunk^=(key&7)
  __shared__ __align__(16) bf16 Vs[4096];   // [feat d][key], chunk^=(d&7)
  const int bh = blockIdx.y;
  const int b = bh >> 4;
  const int h = bh & 15;
  const int q0 = blockIdx.x * 128;
  const int tid = threadIdx.x;
  const int wid = tid >> 6;
  const int lane = tid & 63;
  const int l15 = lane & 15;
  const int quad = lane >> 4;

  // Q fragments (B-operand: n=qrow=l15, k=feat quad*8+j)
  bf16x8 aq[2][2];
#pragma unroll
  for (int i = 0; i < 2; ++i) {
    const int qrow = q0 + wid * 32 + i * 16 + l15;
    const size_t qbase = (size_t)(b * S_LEN + qrow) * (3 * DIM) + h * HEADD;
    aq[i][0] = *(const bf16x8*)(qkv + qbase + quad * 8);
    aq[i][1] = *(const bf16x8*)(qkv + qbase + 32 + quad * 8);
  }

  const int rstage = tid & 63;       // one row per lane (bank-floor writes)
  const int kbase = tid >> 6;        // chunk 0..3 (+4 on round 2)
  const float cexp = 0.125f * 1.44269504f;   // scale * log2(e)

  f32x4 oacc[2][4] = {};
  float psum[2] = {0.f, 0.f};

  for (int kt = 0; kt < S_LEN; kt += 64) {
    __syncthreads();   // previous iteration's reads done before restage
    const bf16* krow = qkv + (size_t)(b * S_LEN + kt + rstage) * 3072 + DIM + h * HEADD;
    const bf16* vrow = VT + (size_t)(bh * 64 + rstage) * S_LEN + kt;
    const int rsw = rstage & 7;
#pragma unroll
    for (int rr = 0; rr < 2; ++rr) {
      const int ck = kbase + 4 * rr;
      const int sw = ((ck ^ rsw) << 3);
      *(bf16x8*)&Ks[rstage * 64 + sw] = *(const bf16x8*)(krow + ck * 8);
      *(bf16x8*)&Vs[rstage * 64 + sw] = *(const bf16x8*)(vrow + ck * 8);
    }
    __syncthreads();

    // S^T = K·Q^T  (A = K rows, B = Q^T): D[key][qrow]
    f32x4 sc[2][4] = {};
#pragma unroll
    for (int hh = 0; hh < 2; ++hh) {
#pragma unroll
      for (int cc = 0; cc < 4; ++cc) {
        const int row = cc * 16 + l15;
        const bf16x8 kf = *(const bf16x8*)&Ks[row * 64 + (((quad + 4 * hh) ^ (l15 & 7)) << 3)];
#pragma unroll
        for (int i = 0; i < 2; ++i)
          sc[i][cc] = __builtin_amdgcn_mfma_f32_16x16x32_bf16(kf, aq[i][hh],
                                                              sc[i][cc], 0, 0, 0);
      }
    }

    // fixed-shift softmax numerator; pack P into A-frags in registers
    s16x4 pf[2][4];
#pragma unroll
    for (int i = 0; i < 2; ++i)
#pragma unroll
      for (int cc = 0; cc < 4; ++cc) {
        bf16x4 pb;
#pragma unroll
        for (int r = 0; r < 4; ++r) {
          const float p = __builtin_amdgcn_exp2f(fmaf(sc[i][cc][r], cexp, -8.0f));
          psum[i] += p;
          pb[r] = (bf16)p;
        }
        pf[i][cc] = __builtin_bit_cast(s16x4, pb);
      }

    // O[qrow][d] += P·V via 16x16x16 (P in regs; V b64 frags from swizzled LDS)
#pragma unroll
    for (int j = 0; j < 4; ++j) {
      const int d = 16 * j + l15;
      const int drow = d * 64;
      const int dsw = d & 7;
#pragma unroll
      for (int cc = 0; cc < 4; ++cc) {
        const int ck = 2 * cc + (quad >> 1);
        const s16x4 vf = *(const s16x4*)&Vs[drow + ((ck ^ dsw) << 3) + ((quad & 1) << 2)];
#pragma unroll
        for (int i = 0; i < 2; ++i)
          oacc[i][j] = __builtin_amdgcn_mfma_f32_16x16x16bf16_1k(pf[i][cc], vf,
                                                                 oacc[i][j], 0, 0, 0);
      }
    }
  }

  // psum lives per-lane for qrow=l15: reduce across quads, then redistribute
#pragma unroll
  for (int i = 0; i < 2; ++i) {
    float ps = psum[i];
    ps += __shfl_xor(ps, 16, 64);
    ps += __shfl_xor(ps, 32, 64);
#pragma unroll
    for (int r = 0; r < 4; ++r) {
      const float invl = 1.0f / __shfl(ps, quad * 4 + r, 64);
      const int m = q0 + wid * 32 + i * 16 + quad * 4 + r;
#pragma unroll
      for (int j = 0; j < 4; ++j)
        out[((size_t)(b * S_LEN + m) * NH + h) * HEADD + j * 16 + l15] =
            (bf16)(oacc[i][j][r] * invl);
    }
  }
}

// ---------------- launcher ----------------
extern "C" void kernel_launch(void* const* d_in, const int* in_sizes, int n_in,
                              void* d_out, int out_size, void* d_ws,
                              size_t ws_size, hipStream_t stream) {
  const float* x = (const float*)d_in[0];
  const float* cosb = (const float*)d_in[1];
  const float* sinb = (const float*)d_in[2];
  const float* cnd = (const float*)d_in[3];
  const float* norm1_w = (const float*)d_in[4];
  const float* Wqkv = (const float*)d_in[5];
  const float* Wout = (const float*)d_in[6];
  const float* q_norm_w = (const float*)d_in[7];
  const float* k_norm_w = (const float*)d_in[8];
  const float* norm2_w = (const float*)d_in[9];
  const float* W1 = (const float*)d_in[10];
  const float* b1 = (const float*)d_in[11];
  const float* W2 = (const float*)d_in[12];
  const float* b2 = (const float*)d_in[13];
  const float* ada_W = (const float*)d_in[14];
  const float* ada_b = (const float*)d_in[15];
  float* out = (float*)d_out;

  char* p = (char*)d_ws;
  float* mod = (float*)p;   p += (size_t)4 * MODD * 4;        // (4,6144) f32
  bf16* WqkvT = (bf16*)p;   p += (size_t)3072 * 1024 * 2;
  bf16* WoutT = (bf16*)p;   p += (size_t)1024 * 1024 * 2;
  bf16* W1T = (bf16*)p;     p += (size_t)4096 * 1024 * 2;
  bf16* W2T = (bf16*)p;     p += (size_t)1024 * 4096 * 2;
  bf16* XN = (bf16*)p;      p += (size_t)NTOK * DIM * 2;      // ln1 out, reused ln2
  bf16* QKV = (bf16*)p;     p += (size_t)NTOK * 3 * DIM * 2;  // qkv, q/k roped in place
  bf16* ATTN = (bf16*)p;    p += (size_t)NTOK * DIM * 2;
  bf16* Hbuf = (bf16*)p;    p += (size_t)NTOK * DFF * 2;
  bf16* VT = Hbuf;  // alias: VT (16.8 MB) lives in Hbuf (67 MB); Hbuf written
                    // only after attention has consumed VT (stream-serial).

  init_mod_kernel<<<96, 256, 0, stream>>>(ada_b, mod);
  ada_gemm_kernel<<<dim3(24, 8), 256, 0, stream>>>(cnd, ada_W, mod);
  transpose_cast_kernel<<<dim3(96, 32), 256, 0, stream>>>(Wqkv, WqkvT, 1024, 3072);
  transpose_cast_kernel<<<dim3(32, 32), 256, 0, stream>>>(Wout, WoutT, 1024, 1024);
  transpose_cast_kernel<<<dim3(128, 32), 256, 0, stream>>>(W1, W1T, 1024, 4096);
  transpose_cast_kernel<<<dim3(32, 128), 256, 0, stream>>>(W2, W2T, 4096, 1024);
  ln_mod_kernel<<<NTOK, 256, 0, stream>>>(x, norm1_w, mod, 0, 1024, XN);
  gemm_bt<0><<<dim3(24, 64), 256, 0, stream>>>(XN, WqkvT, QKV, nullptr, nullptr,
                                               nullptr, nullptr, NTOK, 3072, 1024);
  rope_kernel<<<NTOK * NH / 4, 256, 0, stream>>>(QKV, cosb, sinb, q_norm_w, k_norm_w);
  vtrans_kernel<<<dim3(32, 64), 256, 0, stream>>>(QKV, VT);
  attn_kernel<<<dim3(16, 64), 256, 0, stream>>>(QKV, VT, ATTN);
  gemm_bt<1><<<dim3(8, 64), 256, 0, stream>>>(ATTN, WoutT, nullptr, out, nullptr,
                                              mod + 2 * 1024, x, NTOK, 1024, 1024);
  ln_mod_kernel<<<NTOK, 256, 0, stream>>>(out, norm2_w, mod, 3 * 1024, 4 * 1024, XN);
  gemm_bt<2><<<dim3(32, 64), 256, 0, stream>>>(XN, W1T, Hbuf, nullptr, b1, nullptr,
                                               nullptr, NTOK, DFF, 1024);
  gemm_bt<3><<<dim3(8, 64), 256, 0, stream>>>(Hbuf, W2T, nullptr, out, b2,
                                              mod + 5 * 1024, out, NTOK, 1024, DFF);
  (void)in_sizes; (void)n_in; (void)out_size; (void)ws_size;
}

// Round 5
// 667.059 us; speedup vs baseline: 1.2796x; 1.0215x over previous
//
#include <hip/hip_runtime.h>
#include <hip/hip_bf16.h>
#include <math.h>

typedef __bf16 bf16;
typedef __bf16 bf16x8 __attribute__((ext_vector_type(8)));
typedef __bf16 bf16x4 __attribute__((ext_vector_type(4)));
typedef float f32x4 __attribute__((ext_vector_type(4)));
typedef short s16x4 __attribute__((ext_vector_type(4)));

#define S_LEN 2048
#define NTOK 8192          // B*S
#define DIM 1024
#define NH 16
#define HEADD 64
#define DFF 4096
#define MODD 6144          // 6*D

// async global->LDS, 16B per lane; LDS side must be wave-uniform base + lane*16
__device__ __forceinline__ void gload_lds16(const bf16* g, bf16* l) {
  __builtin_amdgcn_global_load_lds(
      (const __attribute__((address_space(1))) void*)g,
      (__attribute__((address_space(3))) void*)l, 16, 0, 0);
}

__device__ __forceinline__ float gelu_tanh(float x) {
  float inner = 0.7978845608028654f * (x + 0.044715f * x * x * x);
  return 0.5f * x * (1.0f + tanhf(inner));
}

// ---------------- mod = c @ ada_W + ada_b ----------------
__global__ __launch_bounds__(256) void init_mod_kernel(
    const float* __restrict__ ada_b, float* __restrict__ mod) {
  int i = blockIdx.x * 256 + threadIdx.x;   // 0..24575
  mod[i] = ada_b[i % MODD];
}

__global__ __launch_bounds__(256) void ada_gemm_kernel(
    const float* __restrict__ cnd, const float* __restrict__ W,
    float* __restrict__ mod) {
  int n = blockIdx.x * 256 + threadIdx.x;   // 0..6143
  int k0 = blockIdx.y * 128;
  float a0 = 0.f, a1 = 0.f, a2 = 0.f, a3 = 0.f;
  for (int k = k0; k < k0 + 128; ++k) {
    float w = W[(size_t)k * MODD + n];
    a0 = fmaf(cnd[k], w, a0);
    a1 = fmaf(cnd[1024 + k], w, a1);
    a2 = fmaf(cnd[2048 + k], w, a2);
    a3 = fmaf(cnd[3072 + k], w, a3);
  }
  atomicAdd(&mod[n], a0);
  atomicAdd(&mod[MODD + n], a1);
  atomicAdd(&mod[2 * MODD + n], a2);
  atomicAdd(&mod[3 * MODD + n], a3);
}

// ---------------- W (K,N) fp32 -> Wt (N,K) bf16 ----------------
__global__ __launch_bounds__(256) void transpose_cast_kernel(
    const float* __restrict__ W, bf16* __restrict__ Wt, int K, int N) {
  __shared__ float tile[32][33];
  int n0 = blockIdx.x * 32, k0 = blockIdx.y * 32;
  int r = threadIdx.x >> 3;
  int c4 = (threadIdx.x & 7) * 4;
  float4 v = *(const float4*)&W[(size_t)(k0 + r) * N + n0 + c4];
  tile[r][c4 + 0] = v.x; tile[r][c4 + 1] = v.y;
  tile[r][c4 + 2] = v.z; tile[r][c4 + 3] = v.w;
  __syncthreads();
  bf16x4 o;
  o[0] = (bf16)tile[c4 + 0][r];
  o[1] = (bf16)tile[c4 + 1][r];
  o[2] = (bf16)tile[c4 + 2][r];
  o[3] = (bf16)tile[c4 + 3][r];
  *(bf16x4*)&Wt[(size_t)(n0 + r) * K + k0 + c4] = o;
}

// ---------------- V part of qkv -> VT[b][h][d][s] ----------------
__global__ __launch_bounds__(256) void vtrans_kernel(
    const bf16* __restrict__ qkv, bf16* __restrict__ VT) {
  __shared__ __align__(16) bf16 t[64][72];
  const int bh = blockIdx.y;
  const int b = bh >> 4, h = bh & 15;
  const int s0 = blockIdx.x * 64;
  const int tid = threadIdx.x;
  {
    const int r = tid >> 2;
    const int c = (tid & 3) * 16;
    const bf16* src =
        qkv + (size_t)(b * S_LEN + s0 + r) * 3072 + 2048 + h * 64 + c;
    *(bf16x8*)&t[r][c] = *(const bf16x8*)src;
    *(bf16x8*)&t[r][c + 8] = *(const bf16x8*)(src + 8);
  }
  __syncthreads();
  {
    const int d = tid & 63;
    const int sc = (tid >> 6) * 16;
    bf16x8 o0, o1;
#pragma unroll
    for (int j = 0; j < 8; ++j) o0[j] = t[sc + j][d];
#pragma unroll
    for (int j = 0; j < 8; ++j) o1[j] = t[sc + 8 + j][d];
    bf16* dst = VT + (size_t)(bh * 64 + d) * S_LEN + s0 + sc;
    *(bf16x8*)dst = o0;
    *(bf16x8*)(dst + 8) = o1;
  }
}

// ---------------- LayerNorm + adaLN modulate -> bf16 ----------------
__global__ __launch_bounds__(256) void ln_mod_kernel(
    const float* __restrict__ x, const float* __restrict__ w,
    const float* __restrict__ mod, int sh_off, int sc_off,
    bf16* __restrict__ out) {
  __shared__ float red[8];
  const int row = blockIdx.x;
  const int b = row >> 11;          // row / 2048
  const int tid = threadIdx.x;
  const float4 v = ((const float4*)(x + (size_t)row * DIM))[tid];
  float s1 = v.x + v.y + v.z + v.w;
  float s2 = v.x * v.x + v.y * v.y + v.z * v.z + v.w * v.w;
  for (int off = 32; off > 0; off >>= 1) {
    s1 += __shfl_down(s1, off, 64);
    s2 += __shfl_down(s2, off, 64);
  }
  const int wid = tid >> 6;
  if ((tid & 63) == 0) { red[wid] = s1; red[4 + wid] = s2; }
  __syncthreads();
  s1 = red[0] + red[1] + red[2] + red[3];
  s2 = red[4] + red[5] + red[6] + red[7];
  const float mu = s1 * (1.0f / DIM);
  const float inv = rsqrtf(s2 * (1.0f / DIM) - mu * mu + 1e-5f);
  const int c = tid * 4;
  const float* mb = mod + (size_t)b * MODD;
  float xs[4] = {v.x, v.y, v.z, v.w};
  bf16x4 o;
#pragma unroll
  for (int j = 0; j < 4; ++j)
    o[j] = (bf16)(((xs[j] - mu) * inv) * w[c + j] * (1.0f + mb[sc_off + c + j]) +
                  mb[sh_off + c + j]);
  *(bf16x4*)(out + (size_t)row * DIM + c) = o;
}

// ---------------- bf16 MFMA GEMM, C = A(M,K) @ Bt(N,K)^T, fused epilogues ----
// MT = M-tile (128 or 64); BK=64 via two BK=32 buffer pairs per barrier pair.
// EPI 0: Cb = bf16(acc)
// EPI 1: Cf = resid + g[b,n]*acc              (Wout proj -> d_out)
// EPI 2: Cb = bf16(gelu(acc + bias))          (W1)
// EPI 3: Cf = resid + g[b,n]*(acc + bias)     (W2 -> d_out)
// EPI 4: qkv: q/k cols get fused RMSNorm+RoPE, v cols plain bf16
template <int EPI, int MT>
__global__ __launch_bounds__(256) void gemm_bt(
    const bf16* __restrict__ A, const bf16* __restrict__ Bt,
    bf16* __restrict__ Cb, float* __restrict__ Cf,
    const float* __restrict__ bias, const float* __restrict__ gmod,
    const float* __restrict__ resid, const float* __restrict__ cosb,
    const float* __restrict__ sinb, const float* __restrict__ qw,
    const float* __restrict__ kw, int M, int N, int K) {
  constexpr int IM = MT / 32;              // acc row-tiles per wave
  __shared__ __align__(16) bf16 As[2][MT * 32];
  __shared__ __align__(16) bf16 Bs[2][128 * 32];
  const int tid = threadIdx.x;
  const int wid = tid >> 6;
  const int lane = tid & 63;
  const int l15 = lane & 15;
  const int quad = lane >> 4;
  const int m0 = blockIdx.y * MT;
  const int n0 = blockIdx.x * 128;
  const int wm = (wid & 1) * (MT / 2);
  const int wn = (wid >> 1) * 64;

  const int r0 = tid >> 2;           // 0..63
  const int cc0 = (tid & 3) * 8;     // k-chunk offset in elements
  const size_t a_base = (size_t)(m0 + r0) * K + cc0;
  const size_t a_base2 = (size_t)(m0 + 64 + r0) * K + cc0;  // MT==128 only
  const size_t b_base = (size_t)(n0 + r0) * K + cc0;
  const size_t b_base2 = (size_t)(n0 + 64 + r0) * K + cc0;

  f32x4 acc[IM][4] = {};

  for (int kt = 0; kt < K; kt += 64) {
    gload_lds16(A + a_base + kt, &As[0][tid * 8]);
    if (MT == 128) gload_lds16(A + a_base2 + kt, &As[0][(256 + tid) * 8]);
    gload_lds16(Bt + b_base + kt, &Bs[0][tid * 8]);
    gload_lds16(Bt + b_base2 + kt, &Bs[0][(256 + tid) * 8]);
    gload_lds16(A + a_base + kt + 32, &As[1][tid * 8]);
    if (MT == 128) gload_lds16(A + a_base2 + kt + 32, &As[1][(256 + tid) * 8]);
    gload_lds16(Bt + b_base + kt + 32, &Bs[1][tid * 8]);
    gload_lds16(Bt + b_base2 + kt + 32, &Bs[1][(256 + tid) * 8]);
    __syncthreads();
#pragma unroll
    for (int half = 0; half < 2; ++half) {
      bf16x8 af[IM], bfr[4];
#pragma unroll
      for (int i = 0; i < IM; ++i)
        af[i] = *(const bf16x8*)&As[half][(wm + i * 16 + l15) * 32 + quad * 8];
#pragma unroll
      for (int j = 0; j < 4; ++j)
        bfr[j] = *(const bf16x8*)&Bs[half][(wn + j * 16 + l15) * 32 + quad * 8];
#pragma unroll
      for (int i = 0; i < IM; ++i)
#pragma unroll
        for (int j = 0; j < 4; ++j)
          acc[i][j] = __builtin_amdgcn_mfma_f32_16x16x32_bf16(af[i], bfr[j],
                                                              acc[i][j], 0, 0, 0);
    }
    __syncthreads();
  }

  if (EPI == 4 && n0 < 2048) {
    // q/k columns: fused RMSNorm (over the 64-dim head) + RoPE.
    // Row m's 64 head dims live in this wave's 4 j-regs x 16 l15-lanes.
    const float* nw = ((n0 + wn) < 1024) ? qw : kw;
    float wv[4];
#pragma unroll
    for (int j = 0; j < 4; ++j) wv[j] = nw[j * 16 + l15];
#pragma unroll
    for (int i = 0; i < IM; ++i) {
#pragma unroll
      for (int r = 0; r < 4; ++r) {
        const int m = m0 + wm + i * 16 + quad * 4 + r;
        const int s = m & (S_LEN - 1);
        float v[4];
        float ss = 0.f;
#pragma unroll
        for (int j = 0; j < 4; ++j) { v[j] = acc[i][j][r]; ss += v[j] * v[j]; }
        ss += __shfl_xor(ss, 1, 64);
        ss += __shfl_xor(ss, 2, 64);
        ss += __shfl_xor(ss, 4, 64);
        ss += __shfl_xor(ss, 8, 64);
        const float inv = rsqrtf(ss * (1.0f / HEADD) + 1e-6f);
        float xn[4];
#pragma unroll
        for (int j = 0; j < 4; ++j) xn[j] = v[j] * inv * wv[j];
#pragma unroll
        for (int j = 0; j < 4; ++j) {
          const int d = j * 16 + l15;
          const float rot = (j < 2) ? -xn[j + 2] : xn[j - 2];
          const float o = xn[j] * cosb[s * HEADD + d] + rot * sinb[s * HEADD + d];
          Cb[(size_t)m * N + n0 + wn + d] = (bf16)o;
        }
      }
    }
    return;
  }

#pragma unroll
  for (int i = 0; i < IM; ++i) {
#pragma unroll
    for (int r = 0; r < 4; ++r) {
      const int m = m0 + wm + i * 16 + quad * 4 + r;   // C row = quad*4+reg
#pragma unroll
      for (int j = 0; j < 4; ++j) {
        const int n = n0 + wn + j * 16 + l15;          // C col = lane&15
        float v = acc[i][j][r];
        if (EPI == 0 || EPI == 4) {
          Cb[(size_t)m * N + n] = (bf16)v;
        } else if (EPI == 1) {
          const int b = m >> 11;
          Cf[(size_t)m * N + n] =
              resid[(size_t)m * N + n] + gmod[(size_t)b * MODD + n] * v;
        } else if (EPI == 2) {
          v += bias[n];
          Cb[(size_t)m * N + n] = (bf16)gelu_tanh(v);
        } else {
          v += bias[n];
          const int b = m >> 11;
          Cf[(size_t)m * N + n] =
              resid[(size_t)m * N + n] + gmod[(size_t)b * MODD + n] * v;
        }
      }
    }
  }
}

// ---------------- flash attention v5: split-S + register prefetch ------------
// S^T = K·Q^T (16x16x32); C-layout (qrow=lane&15, key=quad*4+reg) equals the
// A-frag layout of 16x16x16, so P=exp(S) stays in registers for P·V.
// Fixed-shift softmax (|s|<=8 post-RMS-norm) makes split partials additive:
// each z-block handles 1024 keys, writes bf16 O-numerator + f32 psum partials.
// Tile t+1's K/V global loads issue before computing tile t (latency hiding).
__global__ __launch_bounds__(256) void attn_kernel(
    const bf16* __restrict__ qkv, const bf16* __restrict__ VT,
    bf16* __restrict__ Opart, float* __restrict__ psumbuf) {
  __shared__ __align__(16) bf16 Ks[4096];   // [key][feat], chunk^=(key&7)
  __shared__ __align__(16) bf16 Vs[4096];   // [feat d][key], chunk^=(d&7)
  const int bh = blockIdx.y;
  const int b = bh >> 4;
  const int h = bh & 15;
  const int q0 = blockIdx.x * 128;
  const int split = blockIdx.z;
  const int tid = threadIdx.x;
  const int wid = tid >> 6;
  const int lane = tid & 63;
  const int l15 = lane & 15;
  const int quad = lane >> 4;

  // Q fragments (B-operand: n=qrow=l15, k=feat quad*8+j)
  bf16x8 aq[2][2];
#pragma unroll
  for (int i = 0; i < 2; ++i) {
    const int qrow = q0 + wid * 32 + i * 16 + l15;
    const size_t qbase = (size_t)(b * S_LEN + qrow) * (3 * DIM) + h * HEADD;
    aq[i][0] = *(const bf16x8*)(qkv + qbase + quad * 8);
    aq[i][1] = *(const bf16x8*)(qkv + qbase + 32 + quad * 8);
  }

  const int rstage = lane;           // one row per lane (bank-floor writes)
  const int rsw = rstage & 7;
  const bf16* krow =
      qkv + (size_t)(b * S_LEN + split * 1024 + rstage) * 3072 + DIM + h * HEADD;
  const bf16* vrow = VT + (size_t)(bh * 64 + rstage) * S_LEN + split * 1024;

  bf16x8 kreg[2], vreg[2];
#pragma unroll
  for (int rr = 0; rr < 2; ++rr) {
    const int ck = wid + 4 * rr;
    kreg[rr] = *(const bf16x8*)(krow + ck * 8);
    vreg[rr] = *(const bf16x8*)(vrow + ck * 8);
  }

  const float cexp = 0.125f * 1.44269504f;   // scale * log2(e)
  f32x4 oacc[2][4] = {};
  float psum[2] = {0.f, 0.f};

  for (int t = 0; t < 16; ++t) {
    __syncthreads();   // previous tile's LDS reads done
#pragma unroll
    for (int rr = 0; rr < 2; ++rr) {
      const int ck = wid + 4 * rr;
      const int sw = ((ck ^ rsw) << 3);
      *(bf16x8*)&Ks[rstage * 64 + sw] = kreg[rr];
      *(bf16x8*)&Vs[rstage * 64 + sw] = vreg[rr];
    }
    __syncthreads();
    if (t < 15) {     // prefetch next tile while computing this one
      krow += 64 * 3072;
      vrow += 64;
#pragma unroll
      for (int rr = 0; rr < 2; ++rr) {
        const int ck = wid + 4 * rr;
        kreg[rr] = *(const bf16x8*)(krow + ck * 8);
        vreg[rr] = *(const bf16x8*)(vrow + ck * 8);
      }
    }

    // S^T = K·Q^T  (A = K rows, B = Q^T): D[key][qrow]
    f32x4 sc[2][4] = {};
#pragma unroll
    for (int hh = 0; hh < 2; ++hh) {
#pragma unroll
      for (int cc = 0; cc < 4; ++cc) {
        const int row = cc * 16 + l15;
        const bf16x8 kf =
            *(const bf16x8*)&Ks[row * 64 + (((quad + 4 * hh) ^ (l15 & 7)) << 3)];
#pragma unroll
        for (int i = 0; i < 2; ++i)
          sc[i][cc] = __builtin_amdgcn_mfma_f32_16x16x32_bf16(kf, aq[i][hh],
                                                              sc[i][cc], 0, 0, 0);
      }
    }

    // fixed-shift softmax numerator; pack P into A-frags in registers
    s16x4 pf[2][4];
#pragma unroll
    for (int i = 0; i < 2; ++i)
#pragma unroll
      for (int cc = 0; cc < 4; ++cc) {
        bf16x4 pb;
#pragma unroll
        for (int r = 0; r < 4; ++r) {
          const float p = __builtin_amdgcn_exp2f(fmaf(sc[i][cc][r], cexp, -8.0f));
          psum[i] += p;
          pb[r] = (bf16)p;
        }
        pf[i][cc] = __builtin_bit_cast(s16x4, pb);
      }

    // O[qrow][d] += P·V via 16x16x16 (P in regs; V b64 frags from swizzled LDS)
#pragma unroll
    for (int j = 0; j < 4; ++j) {
      const int d = 16 * j + l15;
      const int drow = d * 64;
      const int dsw = d & 7;
#pragma unroll
      for (int cc = 0; cc < 4; ++cc) {
        const int ck = 2 * cc + (quad >> 1);
        const s16x4 vf =
            *(const s16x4*)&Vs[drow + ((ck ^ dsw) << 3) + ((quad & 1) << 2)];
#pragma unroll
        for (int i = 0; i < 2; ++i)
          oacc[i][j] = __builtin_amdgcn_mfma_f32_16x16x16bf16_1k(pf[i][cc], vf,
                                                                 oacc[i][j], 0, 0, 0);
      }
    }
  }

  // store partials (no division here; combine in attn_reduce_kernel)
#pragma unroll
  for (int i = 0; i < 2; ++i) {
    float ps = psum[i];
    ps += __shfl_xor(ps, 16, 64);
    ps += __shfl_xor(ps, 32, 64);
    if (lane < 16) {
      const int qrow = q0 + wid * 32 + i * 16 + lane;
      psumbuf[(size_t)split * (NTOK * NH) + (size_t)(b * S_LEN + qrow) * NH + h] = ps;
    }
#pragma unroll
    for (int r = 0; r < 4; ++r) {
      const int m = q0 + wid * 32 + i * 16 + quad * 4 + r;
#pragma unroll
      for (int j = 0; j < 4; ++j)
        Opart[(size_t)split * (NTOK * DIM) +
              ((size_t)(b * S_LEN + m) * NH + h) * HEADD + j * 16 + l15] =
            (bf16)oacc[i][j][r];
    }
  }
}

// ---------------- combine split-S partials: ATTN = (O0+O1)/(l0+l1) ----------
__global__ __launch_bounds__(256) void attn_reduce_kernel(
    const bf16* __restrict__ Opart, const float* __restrict__ psumbuf,
    bf16* __restrict__ attn) {
  const int g = blockIdx.x * 256 + threadIdx.x;   // 0..1048575
  const int token = g >> 7;
  const int rem = g & 127;
  const int h = rem >> 3;
  const int d0 = (rem & 7) * 8;
  const size_t off = ((size_t)token * NH + h) * HEADD + d0;
  const bf16x8 o0 = *(const bf16x8*)(Opart + off);
  const bf16x8 o1 = *(const bf16x8*)(Opart + (size_t)NTOK * DIM + off);
  const float l = psumbuf[token * NH + h] + psumbuf[NTOK * NH + token * NH + h];
  const float invl = 1.0f / l;
  bf16x8 o;
#pragma unroll
  for (int j = 0; j < 8; ++j)
    o[j] = (bf16)(((float)o0[j] + (float)o1[j]) * invl);
  *(bf16x8*)(attn + off) = o;
}

// ---------------- launcher ----------------
extern "C" void kernel_launch(void* const* d_in, const int* in_sizes, int n_in,
                              void* d_out, int out_size, void* d_ws,
                              size_t ws_size, hipStream_t stream) {
  const float* x = (const float*)d_in[0];
  const float* cosb = (const float*)d_in[1];
  const float* sinb = (const float*)d_in[2];
  const float* cnd = (const float*)d_in[3];
  const float* norm1_w = (const float*)d_in[4];
  const float* Wqkv = (const float*)d_in[5];
  const float* Wout = (const float*)d_in[6];
  const float* q_norm_w = (const float*)d_in[7];
  const float* k_norm_w = (const float*)d_in[8];
  const float* norm2_w = (const float*)d_in[9];
  const float* W1 = (const float*)d_in[10];
  const float* b1 = (const float*)d_in[11];
  const float* W2 = (const float*)d_in[12];
  const float* b2 = (const float*)d_in[13];
  const float* ada_W = (const float*)d_in[14];
  const float* ada_b = (const float*)d_in[15];
  float* out = (float*)d_out;

  char* p = (char*)d_ws;
  float* mod = (float*)p;   p += (size_t)4 * MODD * 4;        // (4,6144) f32
  bf16* WqkvT = (bf16*)p;   p += (size_t)3072 * 1024 * 2;
  bf16* WoutT = (bf16*)p;   p += (size_t)1024 * 1024 * 2;
  bf16* W1T = (bf16*)p;     p += (size_t)4096 * 1024 * 2;
  bf16* W2T = (bf16*)p;     p += (size_t)1024 * 4096 * 2;
  bf16* XN = (bf16*)p;      p += (size_t)NTOK * DIM * 2;      // ln1 out, reused ln2
  bf16* QKV = (bf16*)p;     p += (size_t)NTOK * 3 * DIM * 2;  // qkv (q/k roped)
  bf16* ATTN = (bf16*)p;    p += (size_t)NTOK * DIM * 2;
  bf16* Hbuf = (bf16*)p;    p += (size_t)NTOK * DFF * 2;
  // aliases inside Hbuf (67 MB): consumed before gemm<2> writes Hbuf
  bf16* VT = Hbuf;                                     // 16.8 MB
  bf16* Opart = Hbuf + (size_t)NTOK * DIM;             // 2 x 16.8 MB
  float* psumbuf = (float*)(Hbuf + (size_t)3 * NTOK * DIM);  // 2 x 0.5 MB

  init_mod_kernel<<<96, 256, 0, stream>>>(ada_b, mod);
  ada_gemm_kernel<<<dim3(24, 8), 256, 0, stream>>>(cnd, ada_W, mod);
  transpose_cast_kernel<<<dim3(96, 32), 256, 0, stream>>>(Wqkv, WqkvT, 1024, 3072);
  transpose_cast_kernel<<<dim3(32, 32), 256, 0, stream>>>(Wout, WoutT, 1024, 1024);
  transpose_cast_kernel<<<dim3(128, 32), 256, 0, stream>>>(W1, W1T, 1024, 4096);
  transpose_cast_kernel<<<dim3(32, 128), 256, 0, stream>>>(W2, W2T, 4096, 1024);
  ln_mod_kernel<<<NTOK, 256, 0, stream>>>(x, norm1_w, mod, 0, 1024, XN);
  gemm_bt<4, 128><<<dim3(24, 64), 256, 0, stream>>>(
      XN, WqkvT, QKV, nullptr, nullptr, nullptr, nullptr, cosb, sinb,
      q_norm_w, k_norm_w, NTOK, 3072, 1024);
  vtrans_kernel<<<dim3(32, 64), 256, 0, stream>>>(QKV, VT);
  attn_kernel<<<dim3(16, 64, 2), 256, 0, stream>>>(QKV, VT, Opart, psumbuf);
  attn_reduce_kernel<<<4096, 256, 0, stream>>>(Opart, psumbuf, ATTN);
  gemm_bt<1, 64><<<dim3(8, 128), 256, 0, stream>>>(
      ATTN, WoutT, nullptr, out, nullptr, mod + 2 * 1024, x, nullptr, nullptr,
      nullptr, nullptr, NTOK, 1024, 1024);
  ln_mod_kernel<<<NTOK, 256, 0, stream>>>(out, norm2_w, mod, 3 * 1024, 4 * 1024, XN);
  gemm_bt<2, 128><<<dim3(32, 64), 256, 0, stream>>>(
      XN, W1T, Hbuf, nullptr, b1, nullptr, nullptr, nullptr, nullptr,
      nullptr, nullptr, NTOK, DFF, 1024);
  gemm_bt<3, 64><<<dim3(8, 128), 256, 0, stream>>>(
      Hbuf, W2T, nullptr, out, b2, mod + 5 * 1024, out, nullptr, nullptr,
      nullptr, nullptr, NTOK, 1024, DFF);
  (void)in_sizes; (void)n_in; (void)out_size; (void)ws_size;
}

// Round 6
// 621.028 us; speedup vs baseline: 1.3745x; 1.0741x over previous
//
#include <hip/hip_runtime.h>
#include <hip/hip_bf16.h>
#include <math.h>

typedef __bf16 bf16;
typedef __bf16 bf16x8 __attribute__((ext_vector_type(8)));
typedef __bf16 bf16x4 __attribute__((ext_vector_type(4)));
typedef float f32x4 __attribute__((ext_vector_type(4)));
typedef short s16x4 __attribute__((ext_vector_type(4)));

#define S_LEN 2048
#define NTOK 8192          // B*S
#define DIM 1024
#define NH 16
#define HEADD 64
#define DFF 4096
#define MODD 6144          // 6*D

__device__ __forceinline__ float gelu_tanh(float x) {
  float inner = 0.7978845608028654f * (x + 0.044715f * x * x * x);
  return 0.5f * x * (1.0f + tanhf(inner));
}

// ---------------- mod = c @ ada_W + ada_b ----------------
__global__ __launch_bounds__(256) void init_mod_kernel(
    const float* __restrict__ ada_b, float* __restrict__ mod) {
  int i = blockIdx.x * 256 + threadIdx.x;   // 0..24575
  mod[i] = ada_b[i % MODD];
}

__global__ __launch_bounds__(256) void ada_gemm_kernel(
    const float* __restrict__ cnd, const float* __restrict__ W,
    float* __restrict__ mod) {
  int n = blockIdx.x * 256 + threadIdx.x;   // 0..6143
  int k0 = blockIdx.y * 128;
  float a0 = 0.f, a1 = 0.f, a2 = 0.f, a3 = 0.f;
  for (int k = k0; k < k0 + 128; ++k) {
    float w = W[(size_t)k * MODD + n];
    a0 = fmaf(cnd[k], w, a0);
    a1 = fmaf(cnd[1024 + k], w, a1);
    a2 = fmaf(cnd[2048 + k], w, a2);
    a3 = fmaf(cnd[3072 + k], w, a3);
  }
  atomicAdd(&mod[n], a0);
  atomicAdd(&mod[MODD + n], a1);
  atomicAdd(&mod[2 * MODD + n], a2);
  atomicAdd(&mod[3 * MODD + n], a3);
}

// ---------------- W (K,N) fp32 -> Wt (N,K) bf16 ----------------
__global__ __launch_bounds__(256) void transpose_cast_kernel(
    const float* __restrict__ W, bf16* __restrict__ Wt, int K, int N) {
  __shared__ float tile[32][33];
  int n0 = blockIdx.x * 32, k0 = blockIdx.y * 32;
  int r = threadIdx.x >> 3;
  int c4 = (threadIdx.x & 7) * 4;
  float4 v = *(const float4*)&W[(size_t)(k0 + r) * N + n0 + c4];
  tile[r][c4 + 0] = v.x; tile[r][c4 + 1] = v.y;
  tile[r][c4 + 2] = v.z; tile[r][c4 + 3] = v.w;
  __syncthreads();
  bf16x4 o;
  o[0] = (bf16)tile[c4 + 0][r];
  o[1] = (bf16)tile[c4 + 1][r];
  o[2] = (bf16)tile[c4 + 2][r];
  o[3] = (bf16)tile[c4 + 3][r];
  *(bf16x4*)&Wt[(size_t)(n0 + r) * K + k0 + c4] = o;
}

// ---------------- V part of qkv -> VT[b][h][d][s] ----------------
__global__ __launch_bounds__(256) void vtrans_kernel(
    const bf16* __restrict__ qkv, bf16* __restrict__ VT) {
  __shared__ __align__(16) bf16 t[64][72];
  const int bh = blockIdx.y;
  const int b = bh >> 4, h = bh & 15;
  const int s0 = blockIdx.x * 64;
  const int tid = threadIdx.x;
  {
    const int r = tid >> 2;
    const int c = (tid & 3) * 16;
    const bf16* src =
        qkv + (size_t)(b * S_LEN + s0 + r) * 3072 + 2048 + h * 64 + c;
    *(bf16x8*)&t[r][c] = *(const bf16x8*)src;
    *(bf16x8*)&t[r][c + 8] = *(const bf16x8*)(src + 8);
  }
  __syncthreads();
  {
    const int d = tid & 63;
    const int sc = (tid >> 6) * 16;
    bf16x8 o0, o1;
#pragma unroll
    for (int j = 0; j < 8; ++j) o0[j] = t[sc + j][d];
#pragma unroll
    for (int j = 0; j < 8; ++j) o1[j] = t[sc + 8 + j][d];
    bf16* dst = VT + (size_t)(bh * 64 + d) * S_LEN + s0 + sc;
    *(bf16x8*)dst = o0;
    *(bf16x8*)(dst + 8) = o1;
  }
}

// ---------------- LayerNorm + adaLN modulate -> bf16 ----------------
__global__ __launch_bounds__(256) void ln_mod_kernel(
    const float* __restrict__ x, const float* __restrict__ w,
    const float* __restrict__ mod, int sh_off, int sc_off,
    bf16* __restrict__ out) {
  __shared__ float red[8];
  const int row = blockIdx.x;
  const int b = row >> 11;          // row / 2048
  const int tid = threadIdx.x;
  const float4 v = ((const float4*)(x + (size_t)row * DIM))[tid];
  float s1 = v.x + v.y + v.z + v.w;
  float s2 = v.x * v.x + v.y * v.y + v.z * v.z + v.w * v.w;
  for (int off = 32; off > 0; off >>= 1) {
    s1 += __shfl_down(s1, off, 64);
    s2 += __shfl_down(s2, off, 64);
  }
  const int wid = tid >> 6;
  if ((tid & 63) == 0) { red[wid] = s1; red[4 + wid] = s2; }
  __syncthreads();
  s1 = red[0] + red[1] + red[2] + red[3];
  s2 = red[4] + red[5] + red[6] + red[7];
  const float mu = s1 * (1.0f / DIM);
  const float inv = rsqrtf(s2 * (1.0f / DIM) - mu * mu + 1e-5f);
  const int c = tid * 4;
  const float* mb = mod + (size_t)b * MODD;
  float xs[4] = {v.x, v.y, v.z, v.w};
  bf16x4 o;
#pragma unroll
  for (int j = 0; j < 4; ++j)
    o[j] = (bf16)(((xs[j] - mu) * inv) * w[c + j] * (1.0f + mb[sc_off + c + j]) +
                  mb[sh_off + c + j]);
  *(bf16x4*)(out + (size_t)row * DIM + c) = o;
}

// ---------------- bf16 MFMA GEMM, C = A(M,K) @ Bt(N,K)^T, fused epilogues ----
// Register-prefetch pipeline: tile t+1's global loads issue right after the
// staging barrier of tile t; the vmcnt wait lands at the ds_write in t+1,
// AFTER a full compute phase — load latency overlapped per-wave (no
// vmcnt(0)-before-barrier drain like global_load_lds).
// EPI 0: Cb = bf16(acc)
// EPI 1: Cf = resid + g[b,n]*acc              (Wout proj -> d_out)
// EPI 2: Cb = bf16(gelu(acc + bias))          (W1)
// EPI 3: Cf = resid + g[b,n]*(acc + bias)     (W2 -> d_out)
// EPI 4: qkv: q/k cols get fused RMSNorm+RoPE, v cols plain bf16
template <int EPI, int MT, int BN>
__global__ __launch_bounds__(256) void gemm_bt(
    const bf16* __restrict__ A, const bf16* __restrict__ Bt,
    bf16* __restrict__ Cb, float* __restrict__ Cf,
    const float* __restrict__ bias, const float* __restrict__ gmod,
    const float* __restrict__ resid, const float* __restrict__ cosb,
    const float* __restrict__ sinb, const float* __restrict__ qw,
    const float* __restrict__ kw, int M, int N, int K) {
  constexpr int IM = MT / 32;              // acc row-tiles per wave
  constexpr int JN = BN / 32;              // acc col-tiles per wave
  constexpr int NA = MT / 64;              // staged 64-row groups of A
  constexpr int NB = BN / 64;
  __shared__ __align__(16) bf16 As[2][MT * 32];
  __shared__ __align__(16) bf16 Bs[2][BN * 32];
  const int tid = threadIdx.x;
  const int wid = tid >> 6;
  const int lane = tid & 63;
  const int l15 = lane & 15;
  const int quad = lane >> 4;
  const int m0 = blockIdx.y * MT;
  const int n0 = blockIdx.x * BN;
  const int wm = (wid & 1) * (MT / 2);
  const int wn = (wid >> 1) * (BN / 2);

  const int r0 = tid >> 2;           // 0..63
  const int cc0 = (tid & 3) * 8;     // k-chunk offset in elements
  const bf16* Ap = A + (size_t)(m0 + r0) * K + cc0;
  const bf16* Bp = Bt + (size_t)(n0 + r0) * K + cc0;

  bf16x8 ar[NA][2], br[NB][2];
#pragma unroll
  for (int g = 0; g < NA; ++g)
#pragma unroll
    for (int hf = 0; hf < 2; ++hf)
      ar[g][hf] = *(const bf16x8*)(Ap + (size_t)g * 64 * K + hf * 32);
#pragma unroll
  for (int g = 0; g < NB; ++g)
#pragma unroll
    for (int hf = 0; hf < 2; ++hf)
      br[g][hf] = *(const bf16x8*)(Bp + (size_t)g * 64 * K + hf * 32);

  f32x4 acc[IM][JN] = {};

  for (int kt = 0; kt < K; kt += 64) {
    __syncthreads();   // previous tile's LDS reads done
#pragma unroll
    for (int g = 0; g < NA; ++g)
#pragma unroll
      for (int hf = 0; hf < 2; ++hf)
        *(bf16x8*)&As[hf][(g * 256 + tid) * 8] = ar[g][hf];
#pragma unroll
    for (int g = 0; g < NB; ++g)
#pragma unroll
      for (int hf = 0; hf < 2; ++hf)
        *(bf16x8*)&Bs[hf][(g * 256 + tid) * 8] = br[g][hf];
    __syncthreads();
    if (kt + 64 < K) {   // prefetch next tile while computing this one
#pragma unroll
      for (int g = 0; g < NA; ++g)
#pragma unroll
        for (int hf = 0; hf < 2; ++hf)
          ar[g][hf] = *(const bf16x8*)(Ap + (size_t)g * 64 * K + kt + 64 + hf * 32);
#pragma unroll
      for (int g = 0; g < NB; ++g)
#pragma unroll
        for (int hf = 0; hf < 2; ++hf)
          br[g][hf] = *(const bf16x8*)(Bp + (size_t)g * 64 * K + kt + 64 + hf * 32);
    }
#pragma unroll
    for (int half = 0; half < 2; ++half) {
      bf16x8 af[IM], bfr[JN];
#pragma unroll
      for (int i = 0; i < IM; ++i)
        af[i] = *(const bf16x8*)&As[half][(wm + i * 16 + l15) * 32 + quad * 8];
#pragma unroll
      for (int j = 0; j < JN; ++j)
        bfr[j] = *(const bf16x8*)&Bs[half][(wn + j * 16 + l15) * 32 + quad * 8];
#pragma unroll
      for (int i = 0; i < IM; ++i)
#pragma unroll
        for (int j = 0; j < JN; ++j)
          acc[i][j] = __builtin_amdgcn_mfma_f32_16x16x32_bf16(af[i], bfr[j],
                                                              acc[i][j], 0, 0, 0);
    }
  }

  if (EPI == 4 && n0 < 2048) {
    // q/k columns: fused RMSNorm (over the 64-dim head) + RoPE.
    const float* nw = ((n0 + wn) < 1024) ? qw : kw;
    float wv[4];
#pragma unroll
    for (int j = 0; j < 4; ++j) wv[j] = nw[j * 16 + l15];
#pragma unroll
    for (int i = 0; i < IM; ++i) {
#pragma unroll
      for (int r = 0; r < 4; ++r) {
        const int m = m0 + wm + i * 16 + quad * 4 + r;
        const int s = m & (S_LEN - 1);
        float v[4];
        float ss = 0.f;
#pragma unroll
        for (int j = 0; j < 4; ++j) { v[j] = acc[i][j][r]; ss += v[j] * v[j]; }
        ss += __shfl_xor(ss, 1, 64);
        ss += __shfl_xor(ss, 2, 64);
        ss += __shfl_xor(ss, 4, 64);
        ss += __shfl_xor(ss, 8, 64);
        const float inv = rsqrtf(ss * (1.0f / HEADD) + 1e-6f);
        float xn[4];
#pragma unroll
        for (int j = 0; j < 4; ++j) xn[j] = v[j] * inv * wv[j];
#pragma unroll
        for (int j = 0; j < 4; ++j) {
          const int d = j * 16 + l15;
          const float rot = (j < 2) ? -xn[j + 2] : xn[j - 2];
          const float o = xn[j] * cosb[s * HEADD + d] + rot * sinb[s * HEADD + d];
          Cb[(size_t)m * N + n0 + wn + d] = (bf16)o;
        }
      }
    }
    return;
  }

#pragma unroll
  for (int i = 0; i < IM; ++i) {
#pragma unroll
    for (int r = 0; r < 4; ++r) {
      const int m = m0 + wm + i * 16 + quad * 4 + r;   // C row = quad*4+reg
#pragma unroll
      for (int j = 0; j < JN; ++j) {
        const int n = n0 + wn + j * 16 + l15;          // C col = lane&15
        float v = acc[i][j][r];
        if (EPI == 0 || EPI == 4) {
          Cb[(size_t)m * N + n] = (bf16)v;
        } else if (EPI == 1) {
          const int b = m >> 11;
          Cf[(size_t)m * N + n] =
              resid[(size_t)m * N + n] + gmod[(size_t)b * MODD + n] * v;
        } else if (EPI == 2) {
          v += bias[n];
          Cb[(size_t)m * N + n] = (bf16)gelu_tanh(v);
        } else {
          v += bias[n];
          const int b = m >> 11;
          Cf[(size_t)m * N + n] =
              resid[(size_t)m * N + n] + gmod[(size_t)b * MODD + n] * v;
        }
      }
    }
  }
}

// ---------------- flash attention: split-S + register prefetch ---------------
// S^T = K·Q^T (16x16x32); C-layout (qrow=lane&15, key=quad*4+reg) equals the
// A-frag layout of 16x16x16, so P=exp(S) stays in registers for P·V.
// Fixed-shift softmax (|s|<=8 post-RMS-norm) makes split partials additive.
__global__ __launch_bounds__(256) void attn_kernel(
    const bf16* __restrict__ qkv, const bf16* __restrict__ VT,
    bf16* __restrict__ Opart, float* __restrict__ psumbuf) {
  __shared__ __align__(16) bf16 Ks[4096];   // [key][feat], chunk^=(key&7)
  __shared__ __align__(16) bf16 Vs[4096];   // [feat d][key], chunk^=(d&7)
  const int bh = blockIdx.y;
  const int b = bh >> 4;
  const int h = bh & 15;
  const int q0 = blockIdx.x * 128;
  const int split = blockIdx.z;
  const int tid = threadIdx.x;
  const int wid = tid >> 6;
  const int lane = tid & 63;
  const int l15 = lane & 15;
  const int quad = lane >> 4;

  // Q fragments (B-operand: n=qrow=l15, k=feat quad*8+j)
  bf16x8 aq[2][2];
#pragma unroll
  for (int i = 0; i < 2; ++i) {
    const int qrow = q0 + wid * 32 + i * 16 + l15;
    const size_t qbase = (size_t)(b * S_LEN + qrow) * (3 * DIM) + h * HEADD;
    aq[i][0] = *(const bf16x8*)(qkv + qbase + quad * 8);
    aq[i][1] = *(const bf16x8*)(qkv + qbase + 32 + quad * 8);
  }

  const int rstage = lane;           // one row per lane (bank-floor writes)
  const int rsw = rstage & 7;
  const bf16* krow =
      qkv + (size_t)(b * S_LEN + split * 1024 + rstage) * 3072 + DIM + h * HEADD;
  const bf16* vrow = VT + (size_t)(bh * 64 + rstage) * S_LEN + split * 1024;

  bf16x8 kreg[2], vreg[2];
#pragma unroll
  for (int rr = 0; rr < 2; ++rr) {
    const int ck = wid + 4 * rr;
    kreg[rr] = *(const bf16x8*)(krow + ck * 8);
    vreg[rr] = *(const bf16x8*)(vrow + ck * 8);
  }

  const float cexp = 0.125f * 1.44269504f;   // scale * log2(e)
  f32x4 oacc[2][4] = {};
  float psum[2] = {0.f, 0.f};

  for (int t = 0; t < 16; ++t) {
    __syncthreads();   // previous tile's LDS reads done
#pragma unroll
    for (int rr = 0; rr < 2; ++rr) {
      const int ck = wid + 4 * rr;
      const int sw = ((ck ^ rsw) << 3);
      *(bf16x8*)&Ks[rstage * 64 + sw] = kreg[rr];
      *(bf16x8*)&Vs[rstage * 64 + sw] = vreg[rr];
    }
    __syncthreads();
    if (t < 15) {     // prefetch next tile while computing this one
      krow += 64 * 3072;
      vrow += 64;
#pragma unroll
      for (int rr = 0; rr < 2; ++rr) {
        const int ck = wid + 4 * rr;
        kreg[rr] = *(const bf16x8*)(krow + ck * 8);
        vreg[rr] = *(const bf16x8*)(vrow + ck * 8);
      }
    }

    // S^T = K·Q^T  (A = K rows, B = Q^T): D[key][qrow]
    f32x4 sc[2][4] = {};
#pragma unroll
    for (int hh = 0; hh < 2; ++hh) {
#pragma unroll
      for (int cc = 0; cc < 4; ++cc) {
        const int row = cc * 16 + l15;
        const bf16x8 kf =
            *(const bf16x8*)&Ks[row * 64 + (((quad + 4 * hh) ^ (l15 & 7)) << 3)];
#pragma unroll
        for (int i = 0; i < 2; ++i)
          sc[i][cc] = __builtin_amdgcn_mfma_f32_16x16x32_bf16(kf, aq[i][hh],
                                                              sc[i][cc], 0, 0, 0);
      }
    }

    // fixed-shift softmax numerator; pack P into A-frags in registers
    s16x4 pf[2][4];
#pragma unroll
    for (int i = 0; i < 2; ++i)
#pragma unroll
      for (int cc = 0; cc < 4; ++cc) {
        bf16x4 pb;
#pragma unroll
        for (int r = 0; r < 4; ++r) {
          const float p = __builtin_amdgcn_exp2f(fmaf(sc[i][cc][r], cexp, -8.0f));
          psum[i] += p;
          pb[r] = (bf16)p;
        }
        pf[i][cc] = __builtin_bit_cast(s16x4, pb);
      }

    // O[qrow][d] += P·V via 16x16x16 (P in regs; V b64 frags from swizzled LDS)
#pragma unroll
    for (int j = 0; j < 4; ++j) {
      const int d = 16 * j + l15;
      const int drow = d * 64;
      const int dsw = d & 7;
#pragma unroll
      for (int cc = 0; cc < 4; ++cc) {
        const int ck = 2 * cc + (quad >> 1);
        const s16x4 vf =
            *(const s16x4*)&Vs[drow + ((ck ^ dsw) << 3) + ((quad & 1) << 2)];
#pragma unroll
        for (int i = 0; i < 2; ++i)
          oacc[i][j] = __builtin_amdgcn_mfma_f32_16x16x16bf16_1k(pf[i][cc], vf,
                                                                 oacc[i][j], 0, 0, 0);
      }
    }
  }

  // store partials (no division here; combine in attn_reduce_kernel)
#pragma unroll
  for (int i = 0; i < 2; ++i) {
    float ps = psum[i];
    ps += __shfl_xor(ps, 16, 64);
    ps += __shfl_xor(ps, 32, 64);
    if (lane < 16) {
      const int qrow = q0 + wid * 32 + i * 16 + lane;
      psumbuf[(size_t)split * (NTOK * NH) + (size_t)(b * S_LEN + qrow) * NH + h] = ps;
    }
#pragma unroll
    for (int r = 0; r < 4; ++r) {
      const int m = q0 + wid * 32 + i * 16 + quad * 4 + r;
#pragma unroll
      for (int j = 0; j < 4; ++j)
        Opart[(size_t)split * (NTOK * DIM) +
              ((size_t)(b * S_LEN + m) * NH + h) * HEADD + j * 16 + l15] =
            (bf16)oacc[i][j][r];
    }
  }
}

// ---------------- combine split-S partials: ATTN = (O0+O1)/(l0+l1) ----------
__global__ __launch_bounds__(256) void attn_reduce_kernel(
    const bf16* __restrict__ Opart, const float* __restrict__ psumbuf,
    bf16* __restrict__ attn) {
  const int g = blockIdx.x * 256 + threadIdx.x;   // 0..1048575
  const int token = g >> 7;
  const int rem = g & 127;
  const int h = rem >> 3;
  const int d0 = (rem & 7) * 8;
  const size_t off = ((size_t)token * NH + h) * HEADD + d0;
  const bf16x8 o0 = *(const bf16x8*)(Opart + off);
  const bf16x8 o1 = *(const bf16x8*)(Opart + (size_t)NTOK * DIM + off);
  const float l = psumbuf[token * NH + h] + psumbuf[NTOK * NH + token * NH + h];
  const float invl = 1.0f / l;
  bf16x8 o;
#pragma unroll
  for (int j = 0; j < 8; ++j)
    o[j] = (bf16)(((float)o0[j] + (float)o1[j]) * invl);
  *(bf16x8*)(attn + off) = o;
}

// ---------------- launcher ----------------
extern "C" void kernel_launch(void* const* d_in, const int* in_sizes, int n_in,
                              void* d_out, int out_size, void* d_ws,
                              size_t ws_size, hipStream_t stream) {
  const float* x = (const float*)d_in[0];
  const float* cosb = (const float*)d_in[1];
  const float* sinb = (const float*)d_in[2];
  const float* cnd = (const float*)d_in[3];
  const float* norm1_w = (const float*)d_in[4];
  const float* Wqkv = (const float*)d_in[5];
  const float* Wout = (const float*)d_in[6];
  const float* q_norm_w = (const float*)d_in[7];
  const float* k_norm_w = (const float*)d_in[8];
  const float* norm2_w = (const float*)d_in[9];
  const float* W1 = (const float*)d_in[10];
  const float* b1 = (const float*)d_in[11];
  const float* W2 = (const float*)d_in[12];
  const float* b2 = (const float*)d_in[13];
  const float* ada_W = (const float*)d_in[14];
  const float* ada_b = (const float*)d_in[15];
  float* out = (float*)d_out;

  char* p = (char*)d_ws;
  float* mod = (float*)p;   p += (size_t)4 * MODD * 4;        // (4,6144) f32
  bf16* WqkvT = (bf16*)p;   p += (size_t)3072 * 1024 * 2;
  bf16* WoutT = (bf16*)p;   p += (size_t)1024 * 1024 * 2;
  bf16* W1T = (bf16*)p;     p += (size_t)4096 * 1024 * 2;
  bf16* W2T = (bf16*)p;     p += (size_t)1024 * 4096 * 2;
  bf16* XN = (bf16*)p;      p += (size_t)NTOK * DIM * 2;      // ln1 out, reused ln2
  bf16* QKV = (bf16*)p;     p += (size_t)NTOK * 3 * DIM * 2;  // qkv (q/k roped)
  bf16* ATTN = (bf16*)p;    p += (size_t)NTOK * DIM * 2;
  bf16* Hbuf = (bf16*)p;    p += (size_t)NTOK * DFF * 2;
  // aliases inside Hbuf (67 MB): consumed before gemm<2> writes Hbuf
  bf16* VT = Hbuf;                                     // 16.8 MB
  bf16* Opart = Hbuf + (size_t)NTOK * DIM;             // 2 x 16.8 MB
  float* psumbuf = (float*)(Hbuf + (size_t)3 * NTOK * DIM);  // 2 x 0.5 MB

  init_mod_kernel<<<96, 256, 0, stream>>>(ada_b, mod);
  ada_gemm_kernel<<<dim3(24, 8), 256, 0, stream>>>(cnd, ada_W, mod);
  transpose_cast_kernel<<<dim3(96, 32), 256, 0, stream>>>(Wqkv, WqkvT, 1024, 3072);
  transpose_cast_kernel<<<dim3(32, 32), 256, 0, stream>>>(Wout, WoutT, 1024, 1024);
  transpose_cast_kernel<<<dim3(128, 32), 256, 0, stream>>>(W1, W1T, 1024, 4096);
  transpose_cast_kernel<<<dim3(32, 128), 256, 0, stream>>>(W2, W2T, 4096, 1024);
  ln_mod_kernel<<<NTOK, 256, 0, stream>>>(x, norm1_w, mod, 0, 1024, XN);
  gemm_bt<4, 128, 128><<<dim3(24, 64), 256, 0, stream>>>(
      XN, WqkvT, QKV, nullptr, nullptr, nullptr, nullptr, cosb, sinb,
      q_norm_w, k_norm_w, NTOK, 3072, 1024);
  vtrans_kernel<<<dim3(32, 64), 256, 0, stream>>>(QKV, VT);
  attn_kernel<<<dim3(16, 64, 2), 256, 0, stream>>>(QKV, VT, Opart, psumbuf);
  attn_reduce_kernel<<<4096, 256, 0, stream>>>(Opart, psumbuf, ATTN);
  gemm_bt<1, 128, 64><<<dim3(16, 64), 256, 0, stream>>>(
      ATTN, WoutT, nullptr, out, nullptr, mod + 2 * 1024, x, nullptr, nullptr,
      nullptr, nullptr, NTOK, 1024, 1024);
  ln_mod_kernel<<<NTOK, 256, 0, stream>>>(out, norm2_w, mod, 3 * 1024, 4 * 1024, XN);
  gemm_bt<2, 128, 128><<<dim3(32, 64), 256, 0, stream>>>(
      XN, W1T, Hbuf, nullptr, b1, nullptr, nullptr, nullptr, nullptr,
      nullptr, nullptr, NTOK, DFF, 1024);
  gemm_bt<3, 128, 64><<<dim3(16, 64), 256, 0, stream>>>(
      Hbuf, W2T, nullptr, out, b2, mod + 5 * 1024, out, nullptr, nullptr,
      nullptr, nullptr, NTOK, 1024, DFF);
  (void)in_sizes; (void)n_in; (void)out_size; (void)ws_size;
}